// Round 1
// baseline (2139.966 us; speedup 1.0000x reference)
//
#include <hip/hip_runtime.h>
#include <hip/hip_bf16.h>

typedef __attribute__((ext_vector_type(8))) short bf16x8;
typedef __attribute__((ext_vector_type(4))) float f32x4;

__device__ inline unsigned short f2bf(float x) {
  unsigned int u = __float_as_uint(x);
  unsigned int r = (u + 0x7fffu + ((u >> 16) & 1u)) >> 16;
  return (unsigned short)r;
}

// ---------------- prep: transpose weights to bf16 [n][k] ----------------
__global__ __launch_bounds__(256) void prep_weights(
    const float* __restrict__ Wm, const float* __restrict__ w0,
    const float* __restrict__ w1, const float* __restrict__ w2,
    const float* __restrict__ Wn,
    unsigned short* __restrict__ CmbT, unsigned short* __restrict__ W0T,
    unsigned short* __restrict__ W1T, unsigned short* __restrict__ W2nT)
{
  int n = blockIdx.x;      // 0..127 : output column
  int k = threadIdx.x;     // 0..255 : input row
  CmbT[n*256 + k] = f2bf(Wm[k*128 + n]);
  W0T [n*256 + k] = f2bf(w0[k*128 + n]);
  W2nT[n*256 + k] = f2bf((k < 128) ? w2[k*128 + n] : Wn[(k-128)*128 + n]);
  if (k < 128) W1T[n*128 + k] = f2bf(w1[k*128 + n]);
}

// ---------------- scatter: S[r][0:128] += nodes[s]; S[r][128:256] += edges[e] ----
__global__ __launch_bounds__(256) void scatter_edges(
    const float* __restrict__ nodes, const float* __restrict__ edges,
    const int* __restrict__ senders, const int* __restrict__ receivers,
    float* __restrict__ S, int E)
{
  int t = blockIdx.x * 256 + threadIdx.x;
  int e = t >> 5;               // 32 threads per edge
  if (e >= E) return;
  int c = t & 31;               // covers f32 columns [4c, 4c+4)
  int s = senders[e];
  int r = receivers[e];
  float4 nv = *reinterpret_cast<const float4*>(nodes + (size_t)s*128 + c*4);
  float4 ev = *reinterpret_cast<const float4*>(edges + (size_t)e*128 + c*4);
  float* d1 = S + (size_t)r*256 + c*4;
  atomicAdd(d1+0, nv.x); atomicAdd(d1+1, nv.y);
  atomicAdd(d1+2, nv.z); atomicAdd(d1+3, nv.w);
  float* d2 = d1 + 128;
  atomicAdd(d2+0, ev.x); atomicAdd(d2+1, ev.y);
  atomicAdd(d2+2, ev.z); atomicAdd(d2+3, ev.w);
}

// ---------------- fused node update: 4 chained MFMA GEMMs + LayerNorm ----------
// A-fragment from swizzled LDS tile (row-major, rowBytes per row, XOR (row&7)<<4)
__device__ inline bf16x8 ldsFragA(const unsigned short* tile, int rowBytes,
                                  int row, int kk, int lg) {
  int byteOff = row * rowBytes + ((((kk << 6) + (lg << 4))) ^ ((row & 7) << 4));
  return *reinterpret_cast<const bf16x8*>(
      reinterpret_cast<const char*>(tile) + byteOff);
}
// B-fragment from global bf16 weight stored [n][k] row-major (kElems per row)
__device__ inline bf16x8 glbFragB(const unsigned short* WT, int kElems,
                                  int n, int lr, int kk, int lg) {
  size_t el = (size_t)(n*16 + lr) * kElems + kk*32 + lg*8;
  return *reinterpret_cast<const bf16x8*>(WT + el);
}

__global__ __launch_bounds__(256) void fused_node(
    const float* __restrict__ S, const float* __restrict__ nodes,
    const unsigned short* __restrict__ CmbT, const unsigned short* __restrict__ W0T,
    const unsigned short* __restrict__ W1T, const unsigned short* __restrict__ W2nT,
    const float* __restrict__ b0, const float* __restrict__ b1,
    const float* __restrict__ b2, const float* __restrict__ gam,
    const float* __restrict__ bet, float* __restrict__ out, int N)
{
  __shared__ unsigned short sA[64*256];   // S-tile; later reused: h0 [0..8k), h1 [8k..16k)
  __shared__ unsigned short sN[64*128];   // nodes tile
  __shared__ unsigned short sAg[64*128];  // aggregated tile

  const int tid  = threadIdx.x;
  const int lane = tid & 63;
  const int wave = tid >> 6;          // 0..3, each wave owns 16 rows
  const int lr = lane & 15;
  const int lg = lane >> 4;
  const int m0 = blockIdx.x * 64;

  // ---- stage S tile: 64 rows x 256 f32 -> bf16 swizzled (512B rows) ----
  #pragma unroll
  for (int it = 0; it < 8; ++it) {
    int c = tid + (it << 8);          // chunk of 8 f32
    int r = c >> 5, cc = c & 31;
    int gr = m0 + r; if (gr > N-1) gr = N-1;
    const float4* src = reinterpret_cast<const float4*>(S + (size_t)gr*256 + cc*8);
    float4 v0 = src[0], v1 = src[1];
    bf16x8 o;
    o[0]=(short)f2bf(v0.x); o[1]=(short)f2bf(v0.y); o[2]=(short)f2bf(v0.z); o[3]=(short)f2bf(v0.w);
    o[4]=(short)f2bf(v1.x); o[5]=(short)f2bf(v1.y); o[6]=(short)f2bf(v1.z); o[7]=(short)f2bf(v1.w);
    int dst = r*512 + ((cc << 4) ^ ((r & 7) << 4));
    *reinterpret_cast<bf16x8*>(reinterpret_cast<char*>(sA) + dst) = o;
  }
  // ---- stage nodes tile: 64 rows x 128 f32 -> bf16 swizzled (256B rows) ----
  #pragma unroll
  for (int it = 0; it < 4; ++it) {
    int c = tid + (it << 8);
    int r = c >> 4, cc = c & 15;
    int gr = m0 + r; if (gr > N-1) gr = N-1;
    const float4* src = reinterpret_cast<const float4*>(nodes + (size_t)gr*128 + cc*8);
    float4 v0 = src[0], v1 = src[1];
    bf16x8 o;
    o[0]=(short)f2bf(v0.x); o[1]=(short)f2bf(v0.y); o[2]=(short)f2bf(v0.z); o[3]=(short)f2bf(v0.w);
    o[4]=(short)f2bf(v1.x); o[5]=(short)f2bf(v1.y); o[6]=(short)f2bf(v1.z); o[7]=(short)f2bf(v1.w);
    int dst = r*256 + ((cc << 4) ^ ((r & 7) << 4));
    *reinterpret_cast<bf16x8*>(reinterpret_cast<char*>(sN) + dst) = o;
  }
  __syncthreads();

  const int arow  = (wave << 4) + lr;          // A row this lane reads
  const int orow0 = (wave << 4) + (lg << 2);   // first D row this lane owns
  f32x4 acc[8] = {};

  // ---- GEMM1: agg = S(64x256) @ Wm ----
  #pragma unroll
  for (int kk = 0; kk < 8; ++kk) {
    bf16x8 a = ldsFragA(sA, 512, arow, kk, lg);
    #pragma unroll
    for (int n = 0; n < 8; ++n) {
      bf16x8 b = glbFragB(CmbT, 256, n, lr, kk, lg);
      acc[n] = __builtin_amdgcn_mfma_f32_16x16x32_bf16(a, b, acc[n], 0, 0, 0);
    }
  }
  #pragma unroll
  for (int n = 0; n < 8; ++n) {
    #pragma unroll
    for (int i = 0; i < 4; ++i) {
      int r = orow0 + i;
      int cb = ((n << 4) + lr) << 1;
      *reinterpret_cast<unsigned short*>(
          reinterpret_cast<char*>(sAg) + r*256 + (cb ^ ((r & 7) << 4))) = f2bf(acc[n][i]);
    }
  }
  __syncthreads();

  // ---- GEMM2: h0 = relu([nodes, agg] @ w0 + b0) ----
  #pragma unroll
  for (int n = 0; n < 8; ++n) { acc[n][0]=0.f; acc[n][1]=0.f; acc[n][2]=0.f; acc[n][3]=0.f; }
  #pragma unroll
  for (int kk = 0; kk < 8; ++kk) {
    bf16x8 a = (kk < 4) ? ldsFragA(sN, 256, arow, kk, lg)
                        : ldsFragA(sAg, 256, arow, kk-4, lg);
    #pragma unroll
    for (int n = 0; n < 8; ++n) {
      bf16x8 b = glbFragB(W0T, 256, n, lr, kk, lg);
      acc[n] = __builtin_amdgcn_mfma_f32_16x16x32_bf16(a, b, acc[n], 0, 0, 0);
    }
  }
  unsigned short* sH0 = sA;            // reuse S-tile space
  unsigned short* sH1 = sA + 64*128;
  #pragma unroll
  for (int n = 0; n < 8; ++n) {
    float bb = b0[(n << 4) + lr];
    #pragma unroll
    for (int i = 0; i < 4; ++i) {
      int r = orow0 + i;
      int cb = ((n << 4) + lr) << 1;
      float x = fmaxf(acc[n][i] + bb, 0.f);
      *reinterpret_cast<unsigned short*>(
          reinterpret_cast<char*>(sH0) + r*256 + (cb ^ ((r & 7) << 4))) = f2bf(x);
    }
  }
  __syncthreads();

  // ---- GEMM3: h1 = relu(h0 @ w1 + b1) ----
  #pragma unroll
  for (int n = 0; n < 8; ++n) { acc[n][0]=0.f; acc[n][1]=0.f; acc[n][2]=0.f; acc[n][3]=0.f; }
  #pragma unroll
  for (int kk = 0; kk < 4; ++kk) {
    bf16x8 a = ldsFragA(sH0, 256, arow, kk, lg);
    #pragma unroll
    for (int n = 0; n < 8; ++n) {
      bf16x8 b = glbFragB(W1T, 128, n, lr, kk, lg);
      acc[n] = __builtin_amdgcn_mfma_f32_16x16x32_bf16(a, b, acc[n], 0, 0, 0);
    }
  }
  #pragma unroll
  for (int n = 0; n < 8; ++n) {
    float bb = b1[(n << 4) + lr];
    #pragma unroll
    for (int i = 0; i < 4; ++i) {
      int r = orow0 + i;
      int cb = ((n << 4) + lr) << 1;
      float x = fmaxf(acc[n][i] + bb, 0.f);
      *reinterpret_cast<unsigned short*>(
          reinterpret_cast<char*>(sH1) + r*256 + (cb ^ ((r & 7) << 4))) = f2bf(x);
    }
  }
  __syncthreads();

  // ---- GEMM4: o = [h1, nodes] @ [w2; Wnode] + b2, then LayerNorm ----
  #pragma unroll
  for (int n = 0; n < 8; ++n) { acc[n][0]=0.f; acc[n][1]=0.f; acc[n][2]=0.f; acc[n][3]=0.f; }
  #pragma unroll
  for (int kk = 0; kk < 8; ++kk) {
    bf16x8 a = (kk < 4) ? ldsFragA(sH1, 256, arow, kk, lg)
                        : ldsFragA(sN, 256, arow, kk-4, lg);
    #pragma unroll
    for (int n = 0; n < 8; ++n) {
      bf16x8 b = glbFragB(W2nT, 256, n, lr, kk, lg);
      acc[n] = __builtin_amdgcn_mfma_f32_16x16x32_bf16(a, b, acc[n], 0, 0, 0);
    }
  }
  // bias add
  #pragma unroll
  for (int n = 0; n < 8; ++n) {
    float bb = b2[(n << 4) + lr];
    #pragma unroll
    for (int i = 0; i < 4; ++i) acc[n][i] += bb;
  }
  // LayerNorm: rows orow0+i live in 16 lanes (same lg group), 8 cols each
  float ps[4], pq[4];
  #pragma unroll
  for (int i = 0; i < 4; ++i) {
    ps[i] = 0.f; pq[i] = 0.f;
    #pragma unroll
    for (int n = 0; n < 8; ++n) { float x = acc[n][i]; ps[i] += x; pq[i] += x*x; }
  }
  #pragma unroll
  for (int msk = 1; msk < 16; msk <<= 1) {
    #pragma unroll
    for (int i = 0; i < 4; ++i) {
      ps[i] += __shfl_xor(ps[i], msk);
      pq[i] += __shfl_xor(pq[i], msk);
    }
  }
  float mean[4], rstd[4];
  #pragma unroll
  for (int i = 0; i < 4; ++i) {
    mean[i] = ps[i] * (1.f/128.f);
    float var = fmaxf(pq[i] * (1.f/128.f) - mean[i]*mean[i], 0.f);
    rstd[i] = rsqrtf(var + 1e-6f);
  }
  #pragma unroll
  for (int n = 0; n < 8; ++n) {
    int col = (n << 4) + lr;
    float g = gam[col], bt = bet[col];
    #pragma unroll
    for (int i = 0; i < 4; ++i) {
      int grow = m0 + orow0 + i;
      if (grow < N)
        out[(size_t)grow*128 + col] = (acc[n][i] - mean[i]) * rstd[i] * g + bt;
    }
  }
}

extern "C" void kernel_launch(void* const* d_in, const int* in_sizes, int n_in,
                              void* d_out, int out_size, void* d_ws, size_t ws_size,
                              hipStream_t stream) {
  const float* nodes     = (const float*)d_in[0];
  const float* edges     = (const float*)d_in[1];
  const int*   senders   = (const int*)d_in[2];
  const int*   receivers = (const int*)d_in[3];
  const float* Wm  = (const float*)d_in[4];
  const float* Wn  = (const float*)d_in[5];
  const float* w0  = (const float*)d_in[6];
  const float* b0  = (const float*)d_in[7];
  const float* w1  = (const float*)d_in[8];
  const float* b1  = (const float*)d_in[9];
  const float* w2  = (const float*)d_in[10];
  const float* b2  = (const float*)d_in[11];
  const float* gam = (const float*)d_in[12];
  const float* bet = (const float*)d_in[13];
  const int N = in_sizes[0] / 128;
  const int E = in_sizes[1] / 128;

  char* ws = (char*)d_ws;
  float* S = (float*)ws;                               // [N][256] f32
  size_t sBytes = (size_t)N * 256 * 4;
  unsigned short* CmbT = (unsigned short*)(ws + sBytes);   // [128][256]
  unsigned short* W0T  = CmbT + 128*256;                   // [128][256]
  unsigned short* W1T  = W0T + 128*256;                    // [128][128]
  unsigned short* W2nT = W1T + 128*128;                    // [128][256]

  hipMemsetAsync(S, 0, sBytes, stream);
  prep_weights<<<128, 256, 0, stream>>>(Wm, w0, w1, w2, Wn, CmbT, W0T, W1T, W2nT);

  int scatterBlocks = (E * 32 + 255) / 256;
  scatter_edges<<<scatterBlocks, 256, 0, stream>>>(nodes, edges, senders, receivers, S, E);

  int nodeBlocks = (N + 63) / 64;
  fused_node<<<nodeBlocks, 256, 0, stream>>>(S, nodes, CmbT, W0T, W1T, W2nT,
                                             b0, b1, b2, gam, bet, (float*)d_out, N);
}

// Round 2
// 436.946 us; speedup vs baseline: 4.8975x; 4.8975x over previous
//
#include <hip/hip_runtime.h>
#include <hip/hip_bf16.h>

typedef __attribute__((ext_vector_type(8))) short bf16x8;
typedef __attribute__((ext_vector_type(4))) float f32x4;

__device__ inline unsigned short f2bf(float x) {
  unsigned int u = __float_as_uint(x);
  unsigned int r = (u + 0x7fffu + ((u >> 16) & 1u)) >> 16;
  return (unsigned short)r;
}

// ---------------- prep: transpose weights to bf16 [n][k] ----------------
__global__ __launch_bounds__(256) void prep_weights(
    const float* __restrict__ Wm, const float* __restrict__ w0,
    const float* __restrict__ w1, const float* __restrict__ w2,
    const float* __restrict__ Wn,
    unsigned short* __restrict__ CmbT, unsigned short* __restrict__ W0T,
    unsigned short* __restrict__ W1T, unsigned short* __restrict__ W2nT)
{
  int n = blockIdx.x;      // 0..127 : output column
  int k = threadIdx.x;     // 0..255 : input row
  CmbT[n*256 + k] = f2bf(Wm[k*128 + n]);
  W0T [n*256 + k] = f2bf(w0[k*128 + n]);
  W2nT[n*256 + k] = f2bf((k < 128) ? w2[k*128 + n] : Wn[(k-128)*128 + n]);
  if (k < 128) W1T[n*128 + k] = f2bf(w1[k*128 + n]);
}

// ---------------- counting sort of edges by receiver ----------------
__global__ __launch_bounds__(256) void hist_recv(
    const int* __restrict__ recv, int* __restrict__ cnt, int E)
{
  int e = blockIdx.x * 256 + threadIdx.x;
  if (e < E) atomicAdd(&cnt[recv[e]], 1);
}

// single-block exclusive scan over N counters -> offs[0..N], cursor[0..N-1]
__global__ __launch_bounds__(1024) void scan_counts(
    const int* __restrict__ cnt, int* __restrict__ offs,
    int* __restrict__ cursor, int N)
{
  __shared__ int part[1024];
  const int t = threadIdx.x;
  const int C = (N + 1023) / 1024;
  const int lo = t * C;
  const int hi = min(lo + C, N);
  int s = 0;
  for (int i = lo; i < hi; ++i) s += cnt[i];
  part[t] = s;
  __syncthreads();
  // Hillis-Steele inclusive scan
  for (int off = 1; off < 1024; off <<= 1) {
    int v = (t >= off) ? part[t - off] : 0;
    __syncthreads();
    part[t] += v;
    __syncthreads();
  }
  int run = part[t] - s;            // exclusive prefix for this chunk
  for (int i = lo; i < hi; ++i) {
    offs[i] = run; cursor[i] = run;
    run += cnt[i];
  }
  if (t == 1023) offs[N] = part[1023];
}

__global__ __launch_bounds__(256) void scatter_ids(
    const int* __restrict__ recv, int* __restrict__ cursor,
    int* __restrict__ sorted, int E)
{
  int e = blockIdx.x * 256 + threadIdx.x;
  if (e >= E) return;
  int pos = atomicAdd(&cursor[recv[e]], 1);
  sorted[pos] = e;
}

// ---------------- aggregate: one wave per node, fp32 regs, no atomics ------
// S[r][0:128] = sum nodes[senders[e]];  S[r][128:256] = sum edges[e]  (bf16 out)
__global__ __launch_bounds__(256) void aggregate(
    const float* __restrict__ nodes, const float* __restrict__ edges,
    const int* __restrict__ senders, const int* __restrict__ offs,
    const int* __restrict__ sorted, unsigned short* __restrict__ S, int N)
{
  int node = blockIdx.x * 4 + (threadIdx.x >> 6);
  if (node >= N) return;
  const int lane = threadIdx.x & 63;
  const int coff = (lane & 31) * 4;
  const bool isNode = lane < 32;
  const int start = offs[node], end = offs[node + 1];
  float4 acc = {0.f, 0.f, 0.f, 0.f};
  for (int j = start; j < end; ++j) {
    int e = sorted[j];
    const float* p = isNode ? (nodes + (size_t)senders[e] * 128 + coff)
                            : (edges + (size_t)e * 128 + coff);
    float4 v = *reinterpret_cast<const float4*>(p);
    acc.x += v.x; acc.y += v.y; acc.z += v.z; acc.w += v.w;
  }
  ushort4 o;
  o.x = f2bf(acc.x); o.y = f2bf(acc.y); o.z = f2bf(acc.z); o.w = f2bf(acc.w);
  *reinterpret_cast<ushort4*>(S + (size_t)node * 256 + lane * 4) = o;
}

// ---------------- fused node update: 4 chained MFMA GEMMs + LayerNorm ----------
__device__ inline bf16x8 ldsFragA(const unsigned short* tile, int rowBytes,
                                  int row, int kk, int lg) {
  int byteOff = row * rowBytes + ((((kk << 6) + (lg << 4))) ^ ((row & 7) << 4));
  return *reinterpret_cast<const bf16x8*>(
      reinterpret_cast<const char*>(tile) + byteOff);
}
__device__ inline bf16x8 glbFragB(const unsigned short* WT, int kElems,
                                  int n, int lr, int kk, int lg) {
  size_t el = (size_t)(n*16 + lr) * kElems + kk*32 + lg*8;
  return *reinterpret_cast<const bf16x8*>(WT + el);
}

__global__ __launch_bounds__(256) void fused_node(
    const unsigned short* __restrict__ S, const float* __restrict__ nodes,
    const unsigned short* __restrict__ CmbT, const unsigned short* __restrict__ W0T,
    const unsigned short* __restrict__ W1T, const unsigned short* __restrict__ W2nT,
    const float* __restrict__ b0, const float* __restrict__ b1,
    const float* __restrict__ b2, const float* __restrict__ gam,
    const float* __restrict__ bet, float* __restrict__ out, int N)
{
  __shared__ unsigned short sA[64*256];   // S-tile; later reused: h0 [0..8k), h1 [8k..16k)
  __shared__ unsigned short sN[64*128];   // nodes tile
  __shared__ unsigned short sAg[64*128];  // aggregated tile

  const int tid  = threadIdx.x;
  const int lane = tid & 63;
  const int wave = tid >> 6;
  const int lr = lane & 15;
  const int lg = lane >> 4;
  const int m0 = blockIdx.x * 64;

  // ---- stage S tile (already bf16): 64 rows x 512B, swizzled ----
  #pragma unroll
  for (int it = 0; it < 8; ++it) {
    int c = tid + (it << 8);
    int r = c >> 5, cc = c & 31;
    int gr = m0 + r; if (gr > N-1) gr = N-1;
    bf16x8 v = *reinterpret_cast<const bf16x8*>(S + (size_t)gr*256 + cc*8);
    int dst = r*512 + ((cc << 4) ^ ((r & 7) << 4));
    *reinterpret_cast<bf16x8*>(reinterpret_cast<char*>(sA) + dst) = v;
  }
  // ---- stage nodes tile: 64 rows x 128 f32 -> bf16 swizzled (256B rows) ----
  #pragma unroll
  for (int it = 0; it < 4; ++it) {
    int c = tid + (it << 8);
    int r = c >> 4, cc = c & 15;
    int gr = m0 + r; if (gr > N-1) gr = N-1;
    const float4* src = reinterpret_cast<const float4*>(nodes + (size_t)gr*128 + cc*8);
    float4 v0 = src[0], v1 = src[1];
    bf16x8 o;
    o[0]=(short)f2bf(v0.x); o[1]=(short)f2bf(v0.y); o[2]=(short)f2bf(v0.z); o[3]=(short)f2bf(v0.w);
    o[4]=(short)f2bf(v1.x); o[5]=(short)f2bf(v1.y); o[6]=(short)f2bf(v1.z); o[7]=(short)f2bf(v1.w);
    int dst = r*256 + ((cc << 4) ^ ((r & 7) << 4));
    *reinterpret_cast<bf16x8*>(reinterpret_cast<char*>(sN) + dst) = o;
  }
  __syncthreads();

  const int arow  = (wave << 4) + lr;
  const int orow0 = (wave << 4) + (lg << 2);
  f32x4 acc[8] = {};

  // ---- GEMM1: agg = S(64x256) @ Wm ----
  #pragma unroll
  for (int kk = 0; kk < 8; ++kk) {
    bf16x8 a = ldsFragA(sA, 512, arow, kk, lg);
    #pragma unroll
    for (int n = 0; n < 8; ++n) {
      bf16x8 b = glbFragB(CmbT, 256, n, lr, kk, lg);
      acc[n] = __builtin_amdgcn_mfma_f32_16x16x32_bf16(a, b, acc[n], 0, 0, 0);
    }
  }
  #pragma unroll
  for (int n = 0; n < 8; ++n) {
    #pragma unroll
    for (int i = 0; i < 4; ++i) {
      int r = orow0 + i;
      int cb = ((n << 4) + lr) << 1;
      *reinterpret_cast<unsigned short*>(
          reinterpret_cast<char*>(sAg) + r*256 + (cb ^ ((r & 7) << 4))) = f2bf(acc[n][i]);
    }
  }
  __syncthreads();

  // ---- GEMM2: h0 = relu([nodes, agg] @ w0 + b0) ----
  #pragma unroll
  for (int n = 0; n < 8; ++n) { acc[n][0]=0.f; acc[n][1]=0.f; acc[n][2]=0.f; acc[n][3]=0.f; }
  #pragma unroll
  for (int kk = 0; kk < 8; ++kk) {
    bf16x8 a = (kk < 4) ? ldsFragA(sN, 256, arow, kk, lg)
                        : ldsFragA(sAg, 256, arow, kk-4, lg);
    #pragma unroll
    for (int n = 0; n < 8; ++n) {
      bf16x8 b = glbFragB(W0T, 256, n, lr, kk, lg);
      acc[n] = __builtin_amdgcn_mfma_f32_16x16x32_bf16(a, b, acc[n], 0, 0, 0);
    }
  }
  unsigned short* sH0 = sA;
  unsigned short* sH1 = sA + 64*128;
  #pragma unroll
  for (int n = 0; n < 8; ++n) {
    float bb = b0[(n << 4) + lr];
    #pragma unroll
    for (int i = 0; i < 4; ++i) {
      int r = orow0 + i;
      int cb = ((n << 4) + lr) << 1;
      float x = fmaxf(acc[n][i] + bb, 0.f);
      *reinterpret_cast<unsigned short*>(
          reinterpret_cast<char*>(sH0) + r*256 + (cb ^ ((r & 7) << 4))) = f2bf(x);
    }
  }
  __syncthreads();

  // ---- GEMM3: h1 = relu(h0 @ w1 + b1) ----
  #pragma unroll
  for (int n = 0; n < 8; ++n) { acc[n][0]=0.f; acc[n][1]=0.f; acc[n][2]=0.f; acc[n][3]=0.f; }
  #pragma unroll
  for (int kk = 0; kk < 4; ++kk) {
    bf16x8 a = ldsFragA(sH0, 256, arow, kk, lg);
    #pragma unroll
    for (int n = 0; n < 8; ++n) {
      bf16x8 b = glbFragB(W1T, 128, n, lr, kk, lg);
      acc[n] = __builtin_amdgcn_mfma_f32_16x16x32_bf16(a, b, acc[n], 0, 0, 0);
    }
  }
  #pragma unroll
  for (int n = 0; n < 8; ++n) {
    float bb = b1[(n << 4) + lr];
    #pragma unroll
    for (int i = 0; i < 4; ++i) {
      int r = orow0 + i;
      int cb = ((n << 4) + lr) << 1;
      float x = fmaxf(acc[n][i] + bb, 0.f);
      *reinterpret_cast<unsigned short*>(
          reinterpret_cast<char*>(sH1) + r*256 + (cb ^ ((r & 7) << 4))) = f2bf(x);
    }
  }
  __syncthreads();

  // ---- GEMM4: o = [h1, nodes] @ [w2; Wnode] + b2, then LayerNorm ----
  #pragma unroll
  for (int n = 0; n < 8; ++n) { acc[n][0]=0.f; acc[n][1]=0.f; acc[n][2]=0.f; acc[n][3]=0.f; }
  #pragma unroll
  for (int kk = 0; kk < 8; ++kk) {
    bf16x8 a = (kk < 4) ? ldsFragA(sH1, 256, arow, kk, lg)
                        : ldsFragA(sN, 256, arow, kk-4, lg);
    #pragma unroll
    for (int n = 0; n < 8; ++n) {
      bf16x8 b = glbFragB(W2nT, 256, n, lr, kk, lg);
      acc[n] = __builtin_amdgcn_mfma_f32_16x16x32_bf16(a, b, acc[n], 0, 0, 0);
    }
  }
  #pragma unroll
  for (int n = 0; n < 8; ++n) {
    float bb = b2[(n << 4) + lr];
    #pragma unroll
    for (int i = 0; i < 4; ++i) acc[n][i] += bb;
  }
  float ps[4], pq[4];
  #pragma unroll
  for (int i = 0; i < 4; ++i) {
    ps[i] = 0.f; pq[i] = 0.f;
    #pragma unroll
    for (int n = 0; n < 8; ++n) { float x = acc[n][i]; ps[i] += x; pq[i] += x*x; }
  }
  #pragma unroll
  for (int msk = 1; msk < 16; msk <<= 1) {
    #pragma unroll
    for (int i = 0; i < 4; ++i) {
      ps[i] += __shfl_xor(ps[i], msk);
      pq[i] += __shfl_xor(pq[i], msk);
    }
  }
  float mean[4], rstd[4];
  #pragma unroll
  for (int i = 0; i < 4; ++i) {
    mean[i] = ps[i] * (1.f/128.f);
    float var = fmaxf(pq[i] * (1.f/128.f) - mean[i]*mean[i], 0.f);
    rstd[i] = rsqrtf(var + 1e-6f);
  }
  #pragma unroll
  for (int n = 0; n < 8; ++n) {
    int col = (n << 4) + lr;
    float g = gam[col], bt = bet[col];
    #pragma unroll
    for (int i = 0; i < 4; ++i) {
      int grow = m0 + orow0 + i;
      if (grow < N)
        out[(size_t)grow*128 + col] = (acc[n][i] - mean[i]) * rstd[i] * g + bt;
    }
  }
}

extern "C" void kernel_launch(void* const* d_in, const int* in_sizes, int n_in,
                              void* d_out, int out_size, void* d_ws, size_t ws_size,
                              hipStream_t stream) {
  const float* nodes     = (const float*)d_in[0];
  const float* edges     = (const float*)d_in[1];
  const int*   senders   = (const int*)d_in[2];
  const int*   receivers = (const int*)d_in[3];
  const float* Wm  = (const float*)d_in[4];
  const float* Wn  = (const float*)d_in[5];
  const float* w0  = (const float*)d_in[6];
  const float* b0  = (const float*)d_in[7];
  const float* w1  = (const float*)d_in[8];
  const float* b1  = (const float*)d_in[9];
  const float* w2  = (const float*)d_in[10];
  const float* b2  = (const float*)d_in[11];
  const float* gam = (const float*)d_in[12];
  const float* bet = (const float*)d_in[13];
  const int N = in_sizes[0] / 128;
  const int E = in_sizes[1] / 128;

  char* ws = (char*)d_ws;
  unsigned short* S = (unsigned short*)ws;                 // [N][256] bf16
  size_t sBytes = (size_t)N * 256 * 2;
  unsigned short* CmbT = (unsigned short*)(ws + sBytes);   // [128][256]
  unsigned short* W0T  = CmbT + 128*256;                   // [128][256]
  unsigned short* W1T  = W0T + 128*256;                    // [128][128]
  unsigned short* W2nT = W1T + 128*128;                    // [128][256]
  int* cnt    = (int*)(W2nT + 128*256);                    // [N]
  int* offs   = cnt + N;                                   // [N+1]
  int* cursor = offs + N + 1;                              // [N]
  int* sorted = cursor + N;                                // [E]

  hipMemsetAsync(cnt, 0, (size_t)N * 4, stream);
  prep_weights<<<128, 256, 0, stream>>>(Wm, w0, w1, w2, Wn, CmbT, W0T, W1T, W2nT);

  int eBlocks = (E + 255) / 256;
  hist_recv<<<eBlocks, 256, 0, stream>>>(receivers, cnt, E);
  scan_counts<<<1, 1024, 0, stream>>>(cnt, offs, cursor, N);
  scatter_ids<<<eBlocks, 256, 0, stream>>>(receivers, cursor, sorted, E);

  int aggBlocks = (N + 3) / 4;
  aggregate<<<aggBlocks, 256, 0, stream>>>(nodes, edges, senders, offs, sorted, S, N);

  int nodeBlocks = (N + 63) / 64;
  fused_node<<<nodeBlocks, 256, 0, stream>>>(S, nodes, CmbT, W0T, W1T, W2nT,
                                             b0, b1, b2, gam, bet, (float*)d_out, N);
}

// Round 3
// 394.458 us; speedup vs baseline: 5.4251x; 1.1077x over previous
//
#include <hip/hip_runtime.h>
#include <hip/hip_bf16.h>

typedef __attribute__((ext_vector_type(8))) short bf16x8;
typedef __attribute__((ext_vector_type(4))) float f32x4;

__device__ inline unsigned short f2bf(float x) {
  unsigned int u = __float_as_uint(x);
  unsigned int r = (u + 0x7fffu + ((u >> 16) & 1u)) >> 16;
  return (unsigned short)r;
}

// ---------------- prep: transpose weights to bf16 [n][k] ----------------
__global__ __launch_bounds__(256) void prep_weights(
    const float* __restrict__ Wm, const float* __restrict__ w0,
    const float* __restrict__ w1, const float* __restrict__ w2,
    const float* __restrict__ Wn,
    unsigned short* __restrict__ CmbT, unsigned short* __restrict__ W0T,
    unsigned short* __restrict__ W1T, unsigned short* __restrict__ W2nT)
{
  int n = blockIdx.x;      // 0..127 : output column
  int k = threadIdx.x;     // 0..255 : input row
  CmbT[n*256 + k] = f2bf(Wm[k*128 + n]);
  W0T [n*256 + k] = f2bf(w0[k*128 + n]);
  W2nT[n*256 + k] = f2bf((k < 128) ? w2[k*128 + n] : Wn[(k-128)*128 + n]);
  if (k < 128) W1T[n*128 + k] = f2bf(w1[k*128 + n]);
}

// ---------------- counting sort of edges by receiver ----------------
__global__ __launch_bounds__(256) void hist_recv(
    const int* __restrict__ recv, int* __restrict__ cnt, int E)
{
  int e = blockIdx.x * 256 + threadIdx.x;
  if (e < E) atomicAdd(&cnt[recv[e]], 1);
}

__global__ __launch_bounds__(1024) void scan_counts(
    const int* __restrict__ cnt, int* __restrict__ offs,
    int* __restrict__ cursor, int N)
{
  __shared__ int part[1024];
  const int t = threadIdx.x;
  const int C = (N + 1023) / 1024;
  const int lo = t * C;
  const int hi = min(lo + C, N);
  int s = 0;
  for (int i = lo; i < hi; ++i) s += cnt[i];
  part[t] = s;
  __syncthreads();
  for (int off = 1; off < 1024; off <<= 1) {
    int v = (t >= off) ? part[t - off] : 0;
    __syncthreads();
    part[t] += v;
    __syncthreads();
  }
  int run = part[t] - s;
  for (int i = lo; i < hi; ++i) {
    offs[i] = run; cursor[i] = run;
    run += cnt[i];
  }
  if (t == 1023) offs[N] = part[1023];
}

// writes both edge id and its sender id in receiver-sorted order
__global__ __launch_bounds__(256) void scatter_ids(
    const int* __restrict__ recv, const int* __restrict__ send,
    int* __restrict__ cursor, int* __restrict__ sorted,
    int* __restrict__ sortedSend, int E)
{
  int e = blockIdx.x * 256 + threadIdx.x;
  if (e >= E) return;
  int pos = atomicAdd(&cursor[recv[e]], 1);
  sorted[pos] = e;
  sortedSend[pos] = send[e];
}

// ---------------- aggregate: one wave per node, 4x unrolled, no atomics ----
__global__ __launch_bounds__(256) void aggregate(
    const float* __restrict__ nodes, const float* __restrict__ edges,
    const int* __restrict__ offs, const int* __restrict__ sorted,
    const int* __restrict__ sortedSend, unsigned short* __restrict__ S, int N)
{
  int node = blockIdx.x * 4 + (threadIdx.x >> 6);
  if (node >= N) return;
  const int lane = threadIdx.x & 63;
  const int coff = (lane & 31) * 4;
  const bool isNode = lane < 32;
  const int start = offs[node], end = offs[node + 1];
  const int* idx = isNode ? sortedSend : sorted;
  const float* base = isNode ? nodes : edges;
  float4 acc = {0.f, 0.f, 0.f, 0.f};
  int j = start;
  for (; j + 4 <= end; j += 4) {
    int e0 = idx[j+0], e1 = idx[j+1], e2 = idx[j+2], e3 = idx[j+3];
    float4 v0 = *reinterpret_cast<const float4*>(base + (size_t)e0*128 + coff);
    float4 v1 = *reinterpret_cast<const float4*>(base + (size_t)e1*128 + coff);
    float4 v2 = *reinterpret_cast<const float4*>(base + (size_t)e2*128 + coff);
    float4 v3 = *reinterpret_cast<const float4*>(base + (size_t)e3*128 + coff);
    acc.x += v0.x + v1.x + v2.x + v3.x;
    acc.y += v0.y + v1.y + v2.y + v3.y;
    acc.z += v0.z + v1.z + v2.z + v3.z;
    acc.w += v0.w + v1.w + v2.w + v3.w;
  }
  for (; j < end; ++j) {
    int e = idx[j];
    float4 v = *reinterpret_cast<const float4*>(base + (size_t)e*128 + coff);
    acc.x += v.x; acc.y += v.y; acc.z += v.z; acc.w += v.w;
  }
  ushort4 o;
  o.x = f2bf(acc.x); o.y = f2bf(acc.y); o.z = f2bf(acc.z); o.w = f2bf(acc.w);
  *reinterpret_cast<ushort4*>(S + (size_t)node * 256 + lane * 4) = o;
}

// ---------------- fused node update: 4 chained MFMA GEMMs + LayerNorm ----------
__device__ inline bf16x8 ldsFragA(const unsigned short* tile, int rowBytes,
                                  int row, int kk, int lg) {
  int byteOff = row * rowBytes + ((((kk << 6) + (lg << 4))) ^ ((row & 7) << 4));
  return *reinterpret_cast<const bf16x8*>(
      reinterpret_cast<const char*>(tile) + byteOff);
}
__device__ inline bf16x8 glbFragB(const unsigned short* WT, int kElems,
                                  int n, int lr, int kk, int lg) {
  size_t el = (size_t)(n*16 + lr) * kElems + kk*32 + lg*8;
  return *reinterpret_cast<const bf16x8*>(WT + el);
}

__global__ __launch_bounds__(256) void fused_node(
    const unsigned short* __restrict__ S, const float* __restrict__ nodes,
    const unsigned short* __restrict__ CmbT, const unsigned short* __restrict__ W0T,
    const unsigned short* __restrict__ W1T, const unsigned short* __restrict__ W2nT,
    const float* __restrict__ b0, const float* __restrict__ b1,
    const float* __restrict__ b2, const float* __restrict__ gam,
    const float* __restrict__ bet, float* __restrict__ out, int N)
{
  __shared__ unsigned short sN[64*128];    // nodes tile (bf16, swizzled)
  __shared__ unsigned short bufA[64*128];  // agg after G1; h1 after G3
  __shared__ unsigned short bufB[64*128];  // h0 after G2

  const int tid  = threadIdx.x;
  const int lane = tid & 63;
  const int wave = tid >> 6;
  const int lr = lane & 15;
  const int lg = lane >> 4;
  const int m0 = blockIdx.x * 64;

  // ---- stage nodes tile: 64 rows x 128 f32 -> bf16 swizzled (256B rows) ----
  #pragma unroll
  for (int it = 0; it < 4; ++it) {
    int c = tid + (it << 8);
    int r = c >> 4, cc = c & 15;
    int gr = m0 + r; if (gr > N-1) gr = N-1;
    const float4* src = reinterpret_cast<const float4*>(nodes + (size_t)gr*128 + cc*8);
    float4 v0 = src[0], v1 = src[1];
    bf16x8 o;
    o[0]=(short)f2bf(v0.x); o[1]=(short)f2bf(v0.y); o[2]=(short)f2bf(v0.z); o[3]=(short)f2bf(v0.w);
    o[4]=(short)f2bf(v1.x); o[5]=(short)f2bf(v1.y); o[6]=(short)f2bf(v1.z); o[7]=(short)f2bf(v1.w);
    int dst = r*256 + ((cc << 4) ^ ((r & 7) << 4));
    *reinterpret_cast<bf16x8*>(reinterpret_cast<char*>(sN) + dst) = o;
  }

  const int arow  = (wave << 4) + lr;
  const int orow0 = (wave << 4) + (lg << 2);
  int garow = m0 + arow; if (garow > N-1) garow = N-1;
  f32x4 acc[8] = {};

  // ---- GEMM1: agg = S(64x256) @ Wm ; A-fragments direct from global S ----
  #pragma unroll
  for (int kk = 0; kk < 8; ++kk) {
    bf16x8 a = *reinterpret_cast<const bf16x8*>(S + (size_t)garow*256 + kk*32 + lg*8);
    #pragma unroll
    for (int n = 0; n < 8; ++n) {
      bf16x8 b = glbFragB(CmbT, 256, n, lr, kk, lg);
      acc[n] = __builtin_amdgcn_mfma_f32_16x16x32_bf16(a, b, acc[n], 0, 0, 0);
    }
  }
  #pragma unroll
  for (int n = 0; n < 8; ++n) {
    #pragma unroll
    for (int i = 0; i < 4; ++i) {
      int r = orow0 + i;
      int cb = ((n << 4) + lr) << 1;
      *reinterpret_cast<unsigned short*>(
          reinterpret_cast<char*>(bufA) + r*256 + (cb ^ ((r & 7) << 4))) = f2bf(acc[n][i]);
    }
  }
  __syncthreads();   // sN + bufA(agg) ready

  // ---- GEMM2: h0 = relu([nodes, agg] @ w0 + b0) -> bufB ----
  #pragma unroll
  for (int n = 0; n < 8; ++n) { acc[n][0]=0.f; acc[n][1]=0.f; acc[n][2]=0.f; acc[n][3]=0.f; }
  #pragma unroll
  for (int kk = 0; kk < 8; ++kk) {
    bf16x8 a = (kk < 4) ? ldsFragA(sN, 256, arow, kk, lg)
                        : ldsFragA(bufA, 256, arow, kk-4, lg);
    #pragma unroll
    for (int n = 0; n < 8; ++n) {
      bf16x8 b = glbFragB(W0T, 256, n, lr, kk, lg);
      acc[n] = __builtin_amdgcn_mfma_f32_16x16x32_bf16(a, b, acc[n], 0, 0, 0);
    }
  }
  #pragma unroll
  for (int n = 0; n < 8; ++n) {
    float bb = b0[(n << 4) + lr];
    #pragma unroll
    for (int i = 0; i < 4; ++i) {
      int r = orow0 + i;
      int cb = ((n << 4) + lr) << 1;
      float x = fmaxf(acc[n][i] + bb, 0.f);
      *reinterpret_cast<unsigned short*>(
          reinterpret_cast<char*>(bufB) + r*256 + (cb ^ ((r & 7) << 4))) = f2bf(x);
    }
  }
  __syncthreads();   // all GEMM2 reads of bufA done; bufB(h0) ready

  // ---- GEMM3: h1 = relu(h0 @ w1 + b1) -> bufA ----
  #pragma unroll
  for (int n = 0; n < 8; ++n) { acc[n][0]=0.f; acc[n][1]=0.f; acc[n][2]=0.f; acc[n][3]=0.f; }
  #pragma unroll
  for (int kk = 0; kk < 4; ++kk) {
    bf16x8 a = ldsFragA(bufB, 256, arow, kk, lg);
    #pragma unroll
    for (int n = 0; n < 8; ++n) {
      bf16x8 b = glbFragB(W1T, 128, n, lr, kk, lg);
      acc[n] = __builtin_amdgcn_mfma_f32_16x16x32_bf16(a, b, acc[n], 0, 0, 0);
    }
  }
  #pragma unroll
  for (int n = 0; n < 8; ++n) {
    float bb = b1[(n << 4) + lr];
    #pragma unroll
    for (int i = 0; i < 4; ++i) {
      int r = orow0 + i;
      int cb = ((n << 4) + lr) << 1;
      float x = fmaxf(acc[n][i] + bb, 0.f);
      *reinterpret_cast<unsigned short*>(
          reinterpret_cast<char*>(bufA) + r*256 + (cb ^ ((r & 7) << 4))) = f2bf(x);
    }
  }
  __syncthreads();   // bufA(h1) ready

  // ---- GEMM4: o = [h1, nodes] @ [w2; Wnode] + b2, then LayerNorm ----
  #pragma unroll
  for (int n = 0; n < 8; ++n) { acc[n][0]=0.f; acc[n][1]=0.f; acc[n][2]=0.f; acc[n][3]=0.f; }
  #pragma unroll
  for (int kk = 0; kk < 8; ++kk) {
    bf16x8 a = (kk < 4) ? ldsFragA(bufA, 256, arow, kk, lg)
                        : ldsFragA(sN, 256, arow, kk-4, lg);
    #pragma unroll
    for (int n = 0; n < 8; ++n) {
      bf16x8 b = glbFragB(W2nT, 256, n, lr, kk, lg);
      acc[n] = __builtin_amdgcn_mfma_f32_16x16x32_bf16(a, b, acc[n], 0, 0, 0);
    }
  }
  #pragma unroll
  for (int n = 0; n < 8; ++n) {
    float bb = b2[(n << 4) + lr];
    #pragma unroll
    for (int i = 0; i < 4; ++i) acc[n][i] += bb;
  }
  float ps[4], pq[4];
  #pragma unroll
  for (int i = 0; i < 4; ++i) {
    ps[i] = 0.f; pq[i] = 0.f;
    #pragma unroll
    for (int n = 0; n < 8; ++n) { float x = acc[n][i]; ps[i] += x; pq[i] += x*x; }
  }
  #pragma unroll
  for (int msk = 1; msk < 16; msk <<= 1) {
    #pragma unroll
    for (int i = 0; i < 4; ++i) {
      ps[i] += __shfl_xor(ps[i], msk);
      pq[i] += __shfl_xor(pq[i], msk);
    }
  }
  float mean[4], rstd[4];
  #pragma unroll
  for (int i = 0; i < 4; ++i) {
    mean[i] = ps[i] * (1.f/128.f);
    float var = fmaxf(pq[i] * (1.f/128.f) - mean[i]*mean[i], 0.f);
    rstd[i] = rsqrtf(var + 1e-6f);
  }
  #pragma unroll
  for (int n = 0; n < 8; ++n) {
    int col = (n << 4) + lr;
    float g = gam[col], bt = bet[col];
    #pragma unroll
    for (int i = 0; i < 4; ++i) {
      int grow = m0 + orow0 + i;
      if (grow < N)
        out[(size_t)grow*128 + col] = (acc[n][i] - mean[i]) * rstd[i] * g + bt;
    }
  }
}

extern "C" void kernel_launch(void* const* d_in, const int* in_sizes, int n_in,
                              void* d_out, int out_size, void* d_ws, size_t ws_size,
                              hipStream_t stream) {
  const float* nodes     = (const float*)d_in[0];
  const float* edges     = (const float*)d_in[1];
  const int*   senders   = (const int*)d_in[2];
  const int*   receivers = (const int*)d_in[3];
  const float* Wm  = (const float*)d_in[4];
  const float* Wn  = (const float*)d_in[5];
  const float* w0  = (const float*)d_in[6];
  const float* b0  = (const float*)d_in[7];
  const float* w1  = (const float*)d_in[8];
  const float* b1  = (const float*)d_in[9];
  const float* w2  = (const float*)d_in[10];
  const float* b2  = (const float*)d_in[11];
  const float* gam = (const float*)d_in[12];
  const float* bet = (const float*)d_in[13];
  const int N = in_sizes[0] / 128;
  const int E = in_sizes[1] / 128;

  char* ws = (char*)d_ws;
  unsigned short* S = (unsigned short*)ws;                 // [N][256] bf16
  size_t sBytes = (size_t)N * 256 * 2;
  unsigned short* CmbT = (unsigned short*)(ws + sBytes);   // [128][256]
  unsigned short* W0T  = CmbT + 128*256;                   // [128][256]
  unsigned short* W1T  = W0T + 128*256;                    // [128][128]
  unsigned short* W2nT = W1T + 128*128;                    // [128][256]
  int* cnt        = (int*)(W2nT + 128*256);                // [N]
  int* offs       = cnt + N;                               // [N+1]
  int* cursor     = offs + N + 1;                          // [N]
  int* sorted     = cursor + N;                            // [E]
  int* sortedSend = sorted + E;                            // [E]

  hipMemsetAsync(cnt, 0, (size_t)N * 4, stream);
  prep_weights<<<128, 256, 0, stream>>>(Wm, w0, w1, w2, Wn, CmbT, W0T, W1T, W2nT);

  int eBlocks = (E + 255) / 256;
  hist_recv<<<eBlocks, 256, 0, stream>>>(receivers, cnt, E);
  scan_counts<<<1, 1024, 0, stream>>>(cnt, offs, cursor, N);
  scatter_ids<<<eBlocks, 256, 0, stream>>>(receivers, senders, cursor, sorted, sortedSend, E);

  int aggBlocks = (N + 3) / 4;
  aggregate<<<aggBlocks, 256, 0, stream>>>(nodes, edges, offs, sorted, sortedSend, S, N);

  int nodeBlocks = (N + 63) / 64;
  fused_node<<<nodeBlocks, 256, 0, stream>>>(S, nodes, CmbT, W0T, W1T, W2nT,
                                             b0, b1, b2, gam, bet, (float*)d_out, N);
}

// Round 4
// 393.091 us; speedup vs baseline: 5.4439x; 1.0035x over previous
//
#include <hip/hip_runtime.h>
#include <hip/hip_bf16.h>

typedef __attribute__((ext_vector_type(8))) short bf16x8;
typedef __attribute__((ext_vector_type(4))) float f32x4;

__device__ inline unsigned short f2bf(float x) {
  unsigned int u = __float_as_uint(x);
  unsigned int r = (u + 0x7fffu + ((u >> 16) & 1u)) >> 16;
  return (unsigned short)r;
}

// ---------------- zero fill (replaces pathological rocclr fill) ----------------
__global__ __launch_bounds__(256) void zero_buf(int* __restrict__ p, int n) {
  int i = blockIdx.x * 256 + threadIdx.x;
  if (i < n) p[i] = 0;
}

// ---------------- prep: transpose weights to bf16 [n][k] ----------------
__global__ __launch_bounds__(256) void prep_weights(
    const float* __restrict__ Wm, const float* __restrict__ w0,
    const float* __restrict__ w1, const float* __restrict__ w2,
    const float* __restrict__ Wn,
    unsigned short* __restrict__ CmbT, unsigned short* __restrict__ W0T,
    unsigned short* __restrict__ W1T, unsigned short* __restrict__ W2nT)
{
  int n = blockIdx.x;      // 0..127 : output column
  int k = threadIdx.x;     // 0..255 : input row
  CmbT[n*256 + k] = f2bf(Wm[k*128 + n]);
  W0T [n*256 + k] = f2bf(w0[k*128 + n]);
  W2nT[n*256 + k] = f2bf((k < 128) ? w2[k*128 + n] : Wn[(k-128)*128 + n]);
  if (k < 128) W1T[n*128 + k] = f2bf(w1[k*128 + n]);
}

// ---------------- counting sort of edges by receiver ----------------
__global__ __launch_bounds__(256) void hist_recv(
    const int* __restrict__ recv, int* __restrict__ cnt, int E)
{
  int e = blockIdx.x * 256 + threadIdx.x;
  if (e < E) atomicAdd(&cnt[recv[e]], 1);
}

__global__ __launch_bounds__(1024) void scan_counts(
    const int* __restrict__ cnt, int* __restrict__ offs,
    int* __restrict__ cursor, int N)
{
  __shared__ int part[1024];
  const int t = threadIdx.x;
  const int C = (N + 1023) / 1024;
  const int lo = t * C;
  const int hi = min(lo + C, N);
  int s = 0;
  for (int i = lo; i < hi; ++i) s += cnt[i];
  part[t] = s;
  __syncthreads();
  for (int off = 1; off < 1024; off <<= 1) {
    int v = (t >= off) ? part[t - off] : 0;
    __syncthreads();
    part[t] += v;
    __syncthreads();
  }
  int run = part[t] - s;
  for (int i = lo; i < hi; ++i) {
    offs[i] = run; cursor[i] = run;
    run += cnt[i];
  }
  if (t == 1023) offs[N] = part[1023];
}

// writes both edge id and its sender id in receiver-sorted order
__global__ __launch_bounds__(256) void scatter_ids(
    const int* __restrict__ recv, const int* __restrict__ send,
    int* __restrict__ cursor, int* __restrict__ sorted,
    int* __restrict__ sortedSend, int E)
{
  int e = blockIdx.x * 256 + threadIdx.x;
  if (e >= E) return;
  int pos = atomicAdd(&cursor[recv[e]], 1);
  sorted[pos] = e;
  sortedSend[pos] = send[e];
}

// ---------------- aggregate: one wave per node, 4x unrolled, no atomics ----
__global__ __launch_bounds__(256) void aggregate(
    const float* __restrict__ nodes, const float* __restrict__ edges,
    const int* __restrict__ offs, const int* __restrict__ sorted,
    const int* __restrict__ sortedSend, unsigned short* __restrict__ S, int N)
{
  int node = blockIdx.x * 4 + (threadIdx.x >> 6);
  if (node >= N) return;
  const int lane = threadIdx.x & 63;
  const int coff = (lane & 31) * 4;
  const bool isNode = lane < 32;
  const int start = offs[node], end = offs[node + 1];
  const int* idx = isNode ? sortedSend : sorted;
  const float* base = isNode ? nodes : edges;
  float4 acc = {0.f, 0.f, 0.f, 0.f};
  int j = start;
  for (; j + 4 <= end; j += 4) {
    int e0 = idx[j+0], e1 = idx[j+1], e2 = idx[j+2], e3 = idx[j+3];
    float4 v0 = *reinterpret_cast<const float4*>(base + (size_t)e0*128 + coff);
    float4 v1 = *reinterpret_cast<const float4*>(base + (size_t)e1*128 + coff);
    float4 v2 = *reinterpret_cast<const float4*>(base + (size_t)e2*128 + coff);
    float4 v3 = *reinterpret_cast<const float4*>(base + (size_t)e3*128 + coff);
    acc.x += v0.x + v1.x + v2.x + v3.x;
    acc.y += v0.y + v1.y + v2.y + v3.y;
    acc.z += v0.z + v1.z + v2.z + v3.z;
    acc.w += v0.w + v1.w + v2.w + v3.w;
  }
  for (; j < end; ++j) {
    int e = idx[j];
    float4 v = *reinterpret_cast<const float4*>(base + (size_t)e*128 + coff);
    acc.x += v.x; acc.y += v.y; acc.z += v.z; acc.w += v.w;
  }
  ushort4 o;
  o.x = f2bf(acc.x); o.y = f2bf(acc.y); o.z = f2bf(acc.z); o.w = f2bf(acc.w);
  *reinterpret_cast<ushort4*>(S + (size_t)node * 256 + lane * 4) = o;
}

// ---------------- fused node update: 4 chained MFMA GEMMs + LayerNorm ----------
__device__ inline bf16x8 ldsFragA(const unsigned short* tile, int rowBytes,
                                  int row, int kk, int lg) {
  int byteOff = row * rowBytes + ((((kk << 6) + (lg << 4))) ^ ((row & 7) << 4));
  return *reinterpret_cast<const bf16x8*>(
      reinterpret_cast<const char*>(tile) + byteOff);
}
__device__ inline bf16x8 glbFragB(const unsigned short* WT, int kElems,
                                  int n, int lr, int kk, int lg) {
  size_t el = (size_t)(n*16 + lr) * kElems + kk*32 + lg*8;
  return *reinterpret_cast<const bf16x8*>(WT + el);
}

__global__ __launch_bounds__(256) void fused_node(
    const unsigned short* __restrict__ S, const float* __restrict__ nodes,
    const unsigned short* __restrict__ CmbT, const unsigned short* __restrict__ W0T,
    const unsigned short* __restrict__ W1T, const unsigned short* __restrict__ W2nT,
    const float* __restrict__ b0, const float* __restrict__ b1,
    const float* __restrict__ b2, const float* __restrict__ gam,
    const float* __restrict__ bet, float* __restrict__ out, int N)
{
  __shared__ unsigned short sN[64*128];    // nodes tile (bf16, swizzled)
  __shared__ unsigned short bufA[64*128];  // agg after G1; h1 after G3
  __shared__ unsigned short bufB[64*128];  // h0 after G2

  const int tid  = threadIdx.x;
  const int lane = tid & 63;
  const int wave = tid >> 6;
  const int lr = lane & 15;
  const int lg = lane >> 4;
  const int m0 = blockIdx.x * 64;

  // ---- stage nodes tile: 64 rows x 128 f32 -> bf16 swizzled (256B rows) ----
  #pragma unroll
  for (int it = 0; it < 4; ++it) {
    int c = tid + (it << 8);
    int r = c >> 4, cc = c & 15;
    int gr = m0 + r; if (gr > N-1) gr = N-1;
    const float4* src = reinterpret_cast<const float4*>(nodes + (size_t)gr*128 + cc*8);
    float4 v0 = src[0], v1 = src[1];
    bf16x8 o;
    o[0]=(short)f2bf(v0.x); o[1]=(short)f2bf(v0.y); o[2]=(short)f2bf(v0.z); o[3]=(short)f2bf(v0.w);
    o[4]=(short)f2bf(v1.x); o[5]=(short)f2bf(v1.y); o[6]=(short)f2bf(v1.z); o[7]=(short)f2bf(v1.w);
    int dst = r*256 + ((cc << 4) ^ ((r & 7) << 4));
    *reinterpret_cast<bf16x8*>(reinterpret_cast<char*>(sN) + dst) = o;
  }

  const int arow  = (wave << 4) + lr;
  const int orow0 = (wave << 4) + (lg << 2);
  int garow = m0 + arow; if (garow > N-1) garow = N-1;
  f32x4 acc[8] = {};

  // ---- GEMM1: agg = S(64x256) @ Wm ; A-fragments direct from global S ----
  #pragma unroll
  for (int kk = 0; kk < 8; ++kk) {
    bf16x8 a = *reinterpret_cast<const bf16x8*>(S + (size_t)garow*256 + kk*32 + lg*8);
    #pragma unroll
    for (int n = 0; n < 8; ++n) {
      bf16x8 b = glbFragB(CmbT, 256, n, lr, kk, lg);
      acc[n] = __builtin_amdgcn_mfma_f32_16x16x32_bf16(a, b, acc[n], 0, 0, 0);
    }
  }
  #pragma unroll
  for (int n = 0; n < 8; ++n) {
    #pragma unroll
    for (int i = 0; i < 4; ++i) {
      int r = orow0 + i;
      int cb = ((n << 4) + lr) << 1;
      *reinterpret_cast<unsigned short*>(
          reinterpret_cast<char*>(bufA) + r*256 + (cb ^ ((r & 7) << 4))) = f2bf(acc[n][i]);
    }
  }
  __syncthreads();   // sN + bufA(agg) ready

  // ---- GEMM2: h0 = relu([nodes, agg] @ w0 + b0) -> bufB ----
  #pragma unroll
  for (int n = 0; n < 8; ++n) { acc[n][0]=0.f; acc[n][1]=0.f; acc[n][2]=0.f; acc[n][3]=0.f; }
  #pragma unroll
  for (int kk = 0; kk < 8; ++kk) {
    bf16x8 a = (kk < 4) ? ldsFragA(sN, 256, arow, kk, lg)
                        : ldsFragA(bufA, 256, arow, kk-4, lg);
    #pragma unroll
    for (int n = 0; n < 8; ++n) {
      bf16x8 b = glbFragB(W0T, 256, n, lr, kk, lg);
      acc[n] = __builtin_amdgcn_mfma_f32_16x16x32_bf16(a, b, acc[n], 0, 0, 0);
    }
  }
  #pragma unroll
  for (int n = 0; n < 8; ++n) {
    float bb = b0[(n << 4) + lr];
    #pragma unroll
    for (int i = 0; i < 4; ++i) {
      int r = orow0 + i;
      int cb = ((n << 4) + lr) << 1;
      float x = fmaxf(acc[n][i] + bb, 0.f);
      *reinterpret_cast<unsigned short*>(
          reinterpret_cast<char*>(bufB) + r*256 + (cb ^ ((r & 7) << 4))) = f2bf(x);
    }
  }
  __syncthreads();   // all GEMM2 reads of bufA done; bufB(h0) ready

  // ---- GEMM3: h1 = relu(h0 @ w1 + b1) -> bufA ----
  #pragma unroll
  for (int n = 0; n < 8; ++n) { acc[n][0]=0.f; acc[n][1]=0.f; acc[n][2]=0.f; acc[n][3]=0.f; }
  #pragma unroll
  for (int kk = 0; kk < 4; ++kk) {
    bf16x8 a = ldsFragA(bufB, 256, arow, kk, lg);
    #pragma unroll
    for (int n = 0; n < 8; ++n) {
      bf16x8 b = glbFragB(W1T, 128, n, lr, kk, lg);
      acc[n] = __builtin_amdgcn_mfma_f32_16x16x32_bf16(a, b, acc[n], 0, 0, 0);
    }
  }
  #pragma unroll
  for (int n = 0; n < 8; ++n) {
    float bb = b1[(n << 4) + lr];
    #pragma unroll
    for (int i = 0; i < 4; ++i) {
      int r = orow0 + i;
      int cb = ((n << 4) + lr) << 1;
      float x = fmaxf(acc[n][i] + bb, 0.f);
      *reinterpret_cast<unsigned short*>(
          reinterpret_cast<char*>(bufA) + r*256 + (cb ^ ((r & 7) << 4))) = f2bf(x);
    }
  }
  __syncthreads();   // bufA(h1) ready

  // ---- GEMM4: o = [h1, nodes] @ [w2; Wnode] + b2, then LayerNorm ----
  #pragma unroll
  for (int n = 0; n < 8; ++n) { acc[n][0]=0.f; acc[n][1]=0.f; acc[n][2]=0.f; acc[n][3]=0.f; }
  #pragma unroll
  for (int kk = 0; kk < 8; ++kk) {
    bf16x8 a = (kk < 4) ? ldsFragA(bufA, 256, arow, kk, lg)
                        : ldsFragA(sN, 256, arow, kk-4, lg);
    #pragma unroll
    for (int n = 0; n < 8; ++n) {
      bf16x8 b = glbFragB(W2nT, 256, n, lr, kk, lg);
      acc[n] = __builtin_amdgcn_mfma_f32_16x16x32_bf16(a, b, acc[n], 0, 0, 0);
    }
  }
  #pragma unroll
  for (int n = 0; n < 8; ++n) {
    float bb = b2[(n << 4) + lr];
    #pragma unroll
    for (int i = 0; i < 4; ++i) acc[n][i] += bb;
  }
  float ps[4], pq[4];
  #pragma unroll
  for (int i = 0; i < 4; ++i) {
    ps[i] = 0.f; pq[i] = 0.f;
    #pragma unroll
    for (int n = 0; n < 8; ++n) { float x = acc[n][i]; ps[i] += x; pq[i] += x*x; }
  }
  #pragma unroll
  for (int msk = 1; msk < 16; msk <<= 1) {
    #pragma unroll
    for (int i = 0; i < 4; ++i) {
      ps[i] += __shfl_xor(ps[i], msk);
      pq[i] += __shfl_xor(pq[i], msk);
    }
  }
  float mean[4], rstd[4];
  #pragma unroll
  for (int i = 0; i < 4; ++i) {
    mean[i] = ps[i] * (1.f/128.f);
    float var = fmaxf(pq[i] * (1.f/128.f) - mean[i]*mean[i], 0.f);
    rstd[i] = rsqrtf(var + 1e-6f);
  }
  #pragma unroll
  for (int n = 0; n < 8; ++n) {
    int col = (n << 4) + lr;
    float g = gam[col], bt = bet[col];
    #pragma unroll
    for (int i = 0; i < 4; ++i) {
      int grow = m0 + orow0 + i;
      if (grow < N)
        out[(size_t)grow*128 + col] = (acc[n][i] - mean[i]) * rstd[i] * g + bt;
    }
  }
}

extern "C" void kernel_launch(void* const* d_in, const int* in_sizes, int n_in,
                              void* d_out, int out_size, void* d_ws, size_t ws_size,
                              hipStream_t stream) {
  const float* nodes     = (const float*)d_in[0];
  const float* edges     = (const float*)d_in[1];
  const int*   senders   = (const int*)d_in[2];
  const int*   receivers = (const int*)d_in[3];
  const float* Wm  = (const float*)d_in[4];
  const float* Wn  = (const float*)d_in[5];
  const float* w0  = (const float*)d_in[6];
  const float* b0  = (const float*)d_in[7];
  const float* w1  = (const float*)d_in[8];
  const float* b1  = (const float*)d_in[9];
  const float* w2  = (const float*)d_in[10];
  const float* b2  = (const float*)d_in[11];
  const float* gam = (const float*)d_in[12];
  const float* bet = (const float*)d_in[13];
  const int N = in_sizes[0] / 128;
  const int E = in_sizes[1] / 128;

  char* ws = (char*)d_ws;
  unsigned short* S = (unsigned short*)ws;                 // [N][256] bf16
  size_t sBytes = (size_t)N * 256 * 2;
  unsigned short* CmbT = (unsigned short*)(ws + sBytes);   // [128][256]
  unsigned short* W0T  = CmbT + 128*256;                   // [128][256]
  unsigned short* W1T  = W0T + 128*256;                    // [128][128]
  unsigned short* W2nT = W1T + 128*128;                    // [128][256]
  int* cnt        = (int*)(W2nT + 128*256);                // [N]
  int* offs       = cnt + N;                               // [N+1]
  int* cursor     = offs + N + 1;                          // [N]
  int* sorted     = cursor + N;                            // [E]
  int* sortedSend = sorted + E;                            // [E]

  zero_buf<<<(N + 255) / 256, 256, 0, stream>>>(cnt, N);
  prep_weights<<<128, 256, 0, stream>>>(Wm, w0, w1, w2, Wn, CmbT, W0T, W1T, W2nT);

  int eBlocks = (E + 255) / 256;
  hist_recv<<<eBlocks, 256, 0, stream>>>(receivers, cnt, E);
  scan_counts<<<1, 1024, 0, stream>>>(cnt, offs, cursor, N);
  scatter_ids<<<eBlocks, 256, 0, stream>>>(receivers, senders, cursor, sorted, sortedSend, E);

  int aggBlocks = (N + 3) / 4;
  aggregate<<<aggBlocks, 256, 0, stream>>>(nodes, edges, offs, sorted, sortedSend, S, N);

  int nodeBlocks = (N + 63) / 64;
  fused_node<<<nodeBlocks, 256, 0, stream>>>(S, nodes, CmbT, W0T, W1T, W2nT,
                                             b0, b1, b2, gam, bet, (float*)d_out, N);
}

// Round 5
// 325.804 us; speedup vs baseline: 6.5683x; 1.2065x over previous
//
#include <hip/hip_runtime.h>
#include <hip/hip_bf16.h>

typedef __attribute__((ext_vector_type(8))) short bf16x8;
typedef __attribute__((ext_vector_type(4))) float f32x4;

__device__ inline unsigned short f2bf(float x) {
  unsigned int u = __float_as_uint(x);
  unsigned int r = (u + 0x7fffu + ((u >> 16) & 1u)) >> 16;
  return (unsigned short)r;
}

// ---------------- zero fill ----------------
__global__ __launch_bounds__(256) void zero_buf(int* __restrict__ p, int n) {
  int i = blockIdx.x * 256 + threadIdx.x;
  if (i < n) p[i] = 0;
}

// ---------------- prep: transpose weights to bf16 [n][k] ----------------
__global__ __launch_bounds__(256) void prep_weights(
    const float* __restrict__ Wm, const float* __restrict__ w0,
    const float* __restrict__ w1, const float* __restrict__ w2,
    const float* __restrict__ Wn,
    unsigned short* __restrict__ CmbT, unsigned short* __restrict__ W0T,
    unsigned short* __restrict__ W1T, unsigned short* __restrict__ W2nT)
{
  int n = blockIdx.x;      // 0..127 : output column
  int k = threadIdx.x;     // 0..255 : input row
  CmbT[n*256 + k] = f2bf(Wm[k*128 + n]);
  W0T [n*256 + k] = f2bf(w0[k*128 + n]);
  W2nT[n*256 + k] = f2bf((k < 128) ? w2[k*128 + n] : Wn[(k-128)*128 + n]);
  if (k < 128) W1T[n*128 + k] = f2bf(w1[k*128 + n]);
}

// ---------------- counting sort of edges by receiver ----------------
__global__ __launch_bounds__(256) void hist_recv(
    const int* __restrict__ recv, int* __restrict__ cnt, int E)
{
  int e = blockIdx.x * 256 + threadIdx.x;
  if (e < E) atomicAdd(&cnt[recv[e]], 1);
}

__global__ __launch_bounds__(1024) void scan_counts(
    const int* __restrict__ cnt, int* __restrict__ offs,
    int* __restrict__ cursor, int N)
{
  __shared__ int part[1024];
  const int t = threadIdx.x;
  const int C = (N + 1023) / 1024;
  const int lo = t * C;
  const int hi = min(lo + C, N);
  int s = 0;
  for (int i = lo; i < hi; ++i) s += cnt[i];
  part[t] = s;
  __syncthreads();
  for (int off = 1; off < 1024; off <<= 1) {
    int v = (t >= off) ? part[t - off] : 0;
    __syncthreads();
    part[t] += v;
    __syncthreads();
  }
  int run = part[t] - s;
  for (int i = lo; i < hi; ++i) {
    offs[i] = run; cursor[i] = run;
    run += cnt[i];
  }
  if (t == 1023) offs[N] = part[1023];
}

__global__ __launch_bounds__(256) void scatter_ids(
    const int* __restrict__ recv, const int* __restrict__ send,
    int* __restrict__ cursor, int* __restrict__ sorted,
    int* __restrict__ sortedSend, int E)
{
  int e = blockIdx.x * 256 + threadIdx.x;
  if (e >= E) return;
  int pos = atomicAdd(&cursor[recv[e]], 1);
  sorted[pos] = e;
  sortedSend[pos] = send[e];
}

// ---------------- aggregate: one wave per node, 8x unrolled ----
__global__ __launch_bounds__(256) void aggregate(
    const float* __restrict__ nodes, const float* __restrict__ edges,
    const int* __restrict__ offs, const int* __restrict__ sorted,
    const int* __restrict__ sortedSend, unsigned short* __restrict__ S, int N)
{
  int node = blockIdx.x * 4 + (threadIdx.x >> 6);
  if (node >= N) return;
  const int lane = threadIdx.x & 63;
  const int coff = (lane & 31) * 4;
  const bool isNode = lane < 32;
  const int start = offs[node], end = offs[node + 1];
  const int* idx = isNode ? sortedSend : sorted;
  const float* base = isNode ? nodes : edges;
  float4 acc = {0.f, 0.f, 0.f, 0.f};
  int j = start;
  for (; j + 8 <= end; j += 8) {
    int e[8];
    #pragma unroll
    for (int k = 0; k < 8; ++k) e[k] = idx[j + k];
    float4 v[8];
    #pragma unroll
    for (int k = 0; k < 8; ++k)
      v[k] = *reinterpret_cast<const float4*>(base + (size_t)e[k]*128 + coff);
    #pragma unroll
    for (int k = 0; k < 8; ++k) {
      acc.x += v[k].x; acc.y += v[k].y; acc.z += v[k].z; acc.w += v[k].w;
    }
  }
  for (; j + 2 <= end; j += 2) {
    int e0 = idx[j], e1 = idx[j+1];
    float4 v0 = *reinterpret_cast<const float4*>(base + (size_t)e0*128 + coff);
    float4 v1 = *reinterpret_cast<const float4*>(base + (size_t)e1*128 + coff);
    acc.x += v0.x + v1.x; acc.y += v0.y + v1.y;
    acc.z += v0.z + v1.z; acc.w += v0.w + v1.w;
  }
  if (j < end) {
    int e = idx[j];
    float4 v = *reinterpret_cast<const float4*>(base + (size_t)e*128 + coff);
    acc.x += v.x; acc.y += v.y; acc.z += v.z; acc.w += v.w;
  }
  ushort4 o;
  o.x = f2bf(acc.x); o.y = f2bf(acc.y); o.z = f2bf(acc.z); o.w = f2bf(acc.w);
  *reinterpret_cast<ushort4*>(S + (size_t)node * 256 + lane * 4) = o;
}

// ---------------- fused node update: column-split waves, B in registers ------
// A-fragment from swizzled LDS tile (row-major, rowBytes per row, XOR (row&7)<<4)
__device__ inline bf16x8 ldsFragA(const unsigned short* tile, int rowBytes,
                                  int row, int kk, int lg) {
  int byteOff = row * rowBytes + ((((kk << 6) + (lg << 4))) ^ ((row & 7) << 4));
  return *reinterpret_cast<const bf16x8*>(
      reinterpret_cast<const char*>(tile) + byteOff);
}
// B-fragment from global bf16 weight stored [n][k] row-major (kElems per row)
__device__ inline bf16x8 glbFragB(const unsigned short* WT, int kElems,
                                  int n, int lr, int kk, int lg) {
  size_t el = (size_t)(n*16 + lr) * kElems + kk*32 + lg*8;
  return *reinterpret_cast<const bf16x8*>(WT + el);
}

__global__ __launch_bounds__(256, 3) void fused_node(
    const unsigned short* __restrict__ S, const float* __restrict__ nodes,
    const unsigned short* __restrict__ CmbT, const unsigned short* __restrict__ W0T,
    const unsigned short* __restrict__ W1T, const unsigned short* __restrict__ W2nT,
    const float* __restrict__ b0, const float* __restrict__ b1,
    const float* __restrict__ b2, const float* __restrict__ gam,
    const float* __restrict__ bet, float* __restrict__ out, int N)
{
  __shared__ unsigned short sS[64*256];   // 32KB S tile; later bufA=[0,16K), bufB=[16K,32K)
  __shared__ unsigned short sN[64*128];   // 16KB nodes tile
  __shared__ float pS[4][64];             // LN partial sums (wave, row)
  __shared__ float pQ[4][64];

  unsigned short* bufA = sS;              // agg after G1; h1 after G3  [64][128]
  unsigned short* bufB = sS + 64*128;     // h0 after G2               [64][128]

  const int tid  = threadIdx.x;
  const int lane = tid & 63;
  const int w    = tid >> 6;           // wave 0..3: owns cols [w*32, w*32+32)
  const int lr = lane & 15;
  const int lg = lane >> 4;
  const int m0 = blockIdx.x * 64;

  // ---- stage S tile (bf16): 64 rows x 512B, swizzled ----
  #pragma unroll
  for (int it = 0; it < 8; ++it) {
    int c = tid + (it << 8);
    int r = c >> 5, cc = c & 31;
    int gr = m0 + r; if (gr > N-1) gr = N-1;
    bf16x8 v = *reinterpret_cast<const bf16x8*>(S + (size_t)gr*256 + cc*8);
    int dst = r*512 + ((cc << 4) ^ ((r & 7) << 4));
    *reinterpret_cast<bf16x8*>(reinterpret_cast<char*>(sS) + dst) = v;
  }
  // ---- stage nodes tile: f32 -> bf16, swizzled 256B rows ----
  #pragma unroll
  for (int it = 0; it < 4; ++it) {
    int c = tid + (it << 8);
    int r = c >> 4, cc = c & 15;
    int gr = m0 + r; if (gr > N-1) gr = N-1;
    const float4* src = reinterpret_cast<const float4*>(nodes + (size_t)gr*128 + cc*8);
    float4 v0 = src[0], v1 = src[1];
    bf16x8 o;
    o[0]=(short)f2bf(v0.x); o[1]=(short)f2bf(v0.y); o[2]=(short)f2bf(v0.z); o[3]=(short)f2bf(v0.w);
    o[4]=(short)f2bf(v1.x); o[5]=(short)f2bf(v1.y); o[6]=(short)f2bf(v1.z); o[7]=(short)f2bf(v1.w);
    int dst = r*256 + ((cc << 4) ^ ((r & 7) << 4));
    *reinterpret_cast<bf16x8*>(reinterpret_cast<char*>(sN) + dst) = o;
  }
  __syncthreads();

  f32x4 acc[4][2] = {};   // [rowblock][nn] ; row = rb*16+lg*4+i, col = w*32+nn*16+lr

  // ======== GEMM1: agg = S(64x256) @ Wm ========
  {
    bf16x8 b[2][8];
    #pragma unroll
    for (int nn = 0; nn < 2; ++nn)
      #pragma unroll
      for (int kk = 0; kk < 8; ++kk)
        b[nn][kk] = glbFragB(CmbT, 256, w*2 + nn, lr, kk, lg);
    #pragma unroll
    for (int rb = 0; rb < 4; ++rb)
      #pragma unroll
      for (int kk = 0; kk < 8; ++kk) {
        bf16x8 a = ldsFragA(sS, 512, rb*16 + lr, kk, lg);
        #pragma unroll
        for (int nn = 0; nn < 2; ++nn)
          acc[rb][nn] = __builtin_amdgcn_mfma_f32_16x16x32_bf16(a, b[nn][kk], acc[rb][nn], 0, 0, 0);
      }
  }
  __syncthreads();   // all sS reads done before bufA overwrite

  // epilogue G1 -> bufA (agg)
  #pragma unroll
  for (int rb = 0; rb < 4; ++rb)
    #pragma unroll
    for (int nn = 0; nn < 2; ++nn) {
      int col = w*32 + nn*16 + lr;
      #pragma unroll
      for (int i = 0; i < 4; ++i) {
        int r = rb*16 + lg*4 + i;
        *reinterpret_cast<unsigned short*>(
            reinterpret_cast<char*>(bufA) + r*256 + ((col << 1) ^ ((r & 7) << 4))) = f2bf(acc[rb][nn][i]);
      }
    }
  __syncthreads();   // bufA(agg) ready

  // ======== GEMM2: h0 = relu([nodes, agg] @ w0 + b0) -> bufB ========
  {
    bf16x8 b[2][8];
    #pragma unroll
    for (int nn = 0; nn < 2; ++nn)
      #pragma unroll
      for (int kk = 0; kk < 8; ++kk)
        b[nn][kk] = glbFragB(W0T, 256, w*2 + nn, lr, kk, lg);
    #pragma unroll
    for (int rb = 0; rb < 4; ++rb)
      #pragma unroll
      for (int nn = 0; nn < 2; ++nn) { acc[rb][nn][0]=0.f; acc[rb][nn][1]=0.f; acc[rb][nn][2]=0.f; acc[rb][nn][3]=0.f; }
    #pragma unroll
    for (int rb = 0; rb < 4; ++rb)
      #pragma unroll
      for (int kk = 0; kk < 8; ++kk) {
        bf16x8 a = (kk < 4) ? ldsFragA(sN, 256, rb*16 + lr, kk, lg)
                            : ldsFragA(bufA, 256, rb*16 + lr, kk-4, lg);
        #pragma unroll
        for (int nn = 0; nn < 2; ++nn)
          acc[rb][nn] = __builtin_amdgcn_mfma_f32_16x16x32_bf16(a, b[nn][kk], acc[rb][nn], 0, 0, 0);
      }
  }
  // epilogue G2 -> bufB (no barrier needed: writes don't touch bufA/sN)
  #pragma unroll
  for (int nn = 0; nn < 2; ++nn) {
    int col = w*32 + nn*16 + lr;
    float bb = b0[col];
    #pragma unroll
    for (int rb = 0; rb < 4; ++rb)
      #pragma unroll
      for (int i = 0; i < 4; ++i) {
        int r = rb*16 + lg*4 + i;
        float x = fmaxf(acc[rb][nn][i] + bb, 0.f);
        *reinterpret_cast<unsigned short*>(
            reinterpret_cast<char*>(bufB) + r*256 + ((col << 1) ^ ((r & 7) << 4))) = f2bf(x);
      }
  }
  __syncthreads();   // bufB(h0) ready

  // ======== GEMM3: h1 = relu(h0 @ w1 + b1) -> bufA ========
  {
    bf16x8 b[2][4];
    #pragma unroll
    for (int nn = 0; nn < 2; ++nn)
      #pragma unroll
      for (int kk = 0; kk < 4; ++kk)
        b[nn][kk] = glbFragB(W1T, 128, w*2 + nn, lr, kk, lg);
    #pragma unroll
    for (int rb = 0; rb < 4; ++rb)
      #pragma unroll
      for (int nn = 0; nn < 2; ++nn) { acc[rb][nn][0]=0.f; acc[rb][nn][1]=0.f; acc[rb][nn][2]=0.f; acc[rb][nn][3]=0.f; }
    #pragma unroll
    for (int rb = 0; rb < 4; ++rb)
      #pragma unroll
      for (int kk = 0; kk < 4; ++kk) {
        bf16x8 a = ldsFragA(bufB, 256, rb*16 + lr, kk, lg);
        #pragma unroll
        for (int nn = 0; nn < 2; ++nn)
          acc[rb][nn] = __builtin_amdgcn_mfma_f32_16x16x32_bf16(a, b[nn][kk], acc[rb][nn], 0, 0, 0);
      }
  }
  __syncthreads();   // all bufB reads done... then write bufA(h1)
  #pragma unroll
  for (int nn = 0; nn < 2; ++nn) {
    int col = w*32 + nn*16 + lr;
    float bb = b1[col];
    #pragma unroll
    for (int rb = 0; rb < 4; ++rb)
      #pragma unroll
      for (int i = 0; i < 4; ++i) {
        int r = rb*16 + lg*4 + i;
        float x = fmaxf(acc[rb][nn][i] + bb, 0.f);
        *reinterpret_cast<unsigned short*>(
            reinterpret_cast<char*>(bufA) + r*256 + ((col << 1) ^ ((r & 7) << 4))) = f2bf(x);
      }
  }
  __syncthreads();   // bufA(h1) ready

  // ======== GEMM4: o = [h1, nodes] @ [w2; Wnode] + b2, LayerNorm ========
  {
    bf16x8 b[2][8];
    #pragma unroll
    for (int nn = 0; nn < 2; ++nn)
      #pragma unroll
      for (int kk = 0; kk < 8; ++kk)
        b[nn][kk] = glbFragB(W2nT, 256, w*2 + nn, lr, kk, lg);
    #pragma unroll
    for (int rb = 0; rb < 4; ++rb)
      #pragma unroll
      for (int nn = 0; nn < 2; ++nn) { acc[rb][nn][0]=0.f; acc[rb][nn][1]=0.f; acc[rb][nn][2]=0.f; acc[rb][nn][3]=0.f; }
    #pragma unroll
    for (int rb = 0; rb < 4; ++rb)
      #pragma unroll
      for (int kk = 0; kk < 8; ++kk) {
        bf16x8 a = (kk < 4) ? ldsFragA(bufA, 256, rb*16 + lr, kk, lg)
                            : ldsFragA(sN, 256, rb*16 + lr, kk-4, lg);
        #pragma unroll
        for (int nn = 0; nn < 2; ++nn)
          acc[rb][nn] = __builtin_amdgcn_mfma_f32_16x16x32_bf16(a, b[nn][kk], acc[rb][nn], 0, 0, 0);
      }
  }
  // bias
  #pragma unroll
  for (int nn = 0; nn < 2; ++nn) {
    float bb = b2[w*32 + nn*16 + lr];
    #pragma unroll
    for (int rb = 0; rb < 4; ++rb)
      #pragma unroll
      for (int i = 0; i < 4; ++i) acc[rb][nn][i] += bb;
  }

  // ---- LayerNorm: cross-wave row reduction via LDS partials ----
  float rs[4][4], rq[4][4];
  #pragma unroll
  for (int rb = 0; rb < 4; ++rb)
    #pragma unroll
    for (int i = 0; i < 4; ++i) {
      float a0 = acc[rb][0][i], a1 = acc[rb][1][i];
      rs[rb][i] = a0 + a1;
      rq[rb][i] = a0*a0 + a1*a1;
    }
  #pragma unroll
  for (int msk = 1; msk < 16; msk <<= 1)
    #pragma unroll
    for (int rb = 0; rb < 4; ++rb)
      #pragma unroll
      for (int i = 0; i < 4; ++i) {
        rs[rb][i] += __shfl_xor(rs[rb][i], msk);
        rq[rb][i] += __shfl_xor(rq[rb][i], msk);
      }
  if (lr == 0) {
    #pragma unroll
    for (int rb = 0; rb < 4; ++rb)
      #pragma unroll
      for (int i = 0; i < 4; ++i) {
        int r = rb*16 + lg*4 + i;
        pS[w][r] = rs[rb][i];
        pQ[w][r] = rq[rb][i];
      }
  }
  __syncthreads();

  float gmul[2], gadd[2];
  #pragma unroll
  for (int nn = 0; nn < 2; ++nn) {
    int col = w*32 + nn*16 + lr;
    gmul[nn] = gam[col]; gadd[nn] = bet[col];
  }
  #pragma unroll
  for (int rb = 0; rb < 4; ++rb)
    #pragma unroll
    for (int i = 0; i < 4; ++i) {
      int r = rb*16 + lg*4 + i;
      float sum = pS[0][r] + pS[1][r] + pS[2][r] + pS[3][r];
      float sq  = pQ[0][r] + pQ[1][r] + pQ[2][r] + pQ[3][r];
      float mean = sum * (1.f/128.f);
      float var  = fmaxf(sq * (1.f/128.f) - mean*mean, 0.f);
      float rstd = rsqrtf(var + 1e-6f);
      int grow = m0 + r;
      if (grow < N) {
        #pragma unroll
        for (int nn = 0; nn < 2; ++nn) {
          int col = w*32 + nn*16 + lr;
          out[(size_t)grow*128 + col] = (acc[rb][nn][i] - mean) * rstd * gmul[nn] + gadd[nn];
        }
      }
    }
}

extern "C" void kernel_launch(void* const* d_in, const int* in_sizes, int n_in,
                              void* d_out, int out_size, void* d_ws, size_t ws_size,
                              hipStream_t stream) {
  const float* nodes     = (const float*)d_in[0];
  const float* edges     = (const float*)d_in[1];
  const int*   senders   = (const int*)d_in[2];
  const int*   receivers = (const int*)d_in[3];
  const float* Wm  = (const float*)d_in[4];
  const float* Wn  = (const float*)d_in[5];
  const float* w0  = (const float*)d_in[6];
  const float* b0  = (const float*)d_in[7];
  const float* w1  = (const float*)d_in[8];
  const float* b1  = (const float*)d_in[9];
  const float* w2  = (const float*)d_in[10];
  const float* b2  = (const float*)d_in[11];
  const float* gam = (const float*)d_in[12];
  const float* bet = (const float*)d_in[13];
  const int N = in_sizes[0] / 128;
  const int E = in_sizes[1] / 128;

  char* ws = (char*)d_ws;
  unsigned short* S = (unsigned short*)ws;                 // [N][256] bf16
  size_t sBytes = (size_t)N * 256 * 2;
  unsigned short* CmbT = (unsigned short*)(ws + sBytes);   // [128][256]
  unsigned short* W0T  = CmbT + 128*256;                   // [128][256]
  unsigned short* W1T  = W0T + 128*256;                    // [128][128]
  unsigned short* W2nT = W1T + 128*128;                    // [128][256]
  int* cnt        = (int*)(W2nT + 128*256);                // [N]
  int* offs       = cnt + N;                               // [N+1]
  int* cursor     = offs + N + 1;                          // [N]
  int* sorted     = cursor + N;                            // [E]
  int* sortedSend = sorted + E;                            // [E]

  zero_buf<<<(N + 255) / 256, 256, 0, stream>>>(cnt, N);
  prep_weights<<<128, 256, 0, stream>>>(Wm, w0, w1, w2, Wn, CmbT, W0T, W1T, W2nT);

  int eBlocks = (E + 255) / 256;
  hist_recv<<<eBlocks, 256, 0, stream>>>(receivers, cnt, E);
  scan_counts<<<1, 1024, 0, stream>>>(cnt, offs, cursor, N);
  scatter_ids<<<eBlocks, 256, 0, stream>>>(receivers, senders, cursor, sorted, sortedSend, E);

  int aggBlocks = (N + 3) / 4;
  aggregate<<<aggBlocks, 256, 0, stream>>>(nodes, edges, offs, sorted, sortedSend, S, N);

  int nodeBlocks = (N + 63) / 64;
  fused_node<<<nodeBlocks, 256, 0, stream>>>(S, nodes, CmbT, W0T, W1T, W2nT,
                                             b0, b1, b2, gam, bet, (float*)d_out, N);
}

// Round 6
// 314.816 us; speedup vs baseline: 6.7975x; 1.0349x over previous
//
#include <hip/hip_runtime.h>
#include <hip/hip_bf16.h>

typedef __attribute__((ext_vector_type(8))) short bf16x8;
typedef __attribute__((ext_vector_type(4))) float f32x4;

__device__ inline unsigned short f2bf(float x) {
  unsigned int u = __float_as_uint(x);
  unsigned int r = (u + 0x7fffu + ((u >> 16) & 1u)) >> 16;
  return (unsigned short)r;
}

// ---------------- prep weights (blocks 0..127) + zero cnt (blocks >=128) ------
__global__ __launch_bounds__(256) void prep_zero(
    const float* __restrict__ Wm, const float* __restrict__ w0,
    const float* __restrict__ w1, const float* __restrict__ w2,
    const float* __restrict__ Wn,
    unsigned short* __restrict__ CmbT, unsigned short* __restrict__ W0T,
    unsigned short* __restrict__ W1T, unsigned short* __restrict__ W2nT,
    int* __restrict__ cnt, int N)
{
  int b = blockIdx.x;
  if (b < 128) {
    int n = b;
    int k = threadIdx.x;
    CmbT[n*256 + k] = f2bf(Wm[k*128 + n]);
    W0T [n*256 + k] = f2bf(w0[k*128 + n]);
    W2nT[n*256 + k] = f2bf((k < 128) ? w2[k*128 + n] : Wn[(k-128)*128 + n]);
    if (k < 128) W1T[n*128 + k] = f2bf(w1[k*128 + n]);
  } else {
    int base = (b - 128) * 2048 + threadIdx.x;
    #pragma unroll
    for (int it = 0; it < 8; ++it) {
      int i = base + it * 256;
      if (i < N) cnt[i] = 0;
    }
  }
}

// ---------------- counting sort of edges by receiver ----------------
__global__ __launch_bounds__(256) void hist_recv(
    const int* __restrict__ recv, int* __restrict__ cnt, int E)
{
  int e = blockIdx.x * 256 + threadIdx.x;
  if (e < E) atomicAdd(&cnt[recv[e]], 1);
}

__global__ __launch_bounds__(1024) void scan_counts(
    const int* __restrict__ cnt, int* __restrict__ offs,
    int* __restrict__ cursor, int N)
{
  __shared__ int part[1024];
  const int t = threadIdx.x;
  const int C = (N + 1023) / 1024;
  const int lo = t * C;
  const int hi = min(lo + C, N);
  int s = 0;
  for (int i = lo; i < hi; ++i) s += cnt[i];
  part[t] = s;
  __syncthreads();
  for (int off = 1; off < 1024; off <<= 1) {
    int v = (t >= off) ? part[t - off] : 0;
    __syncthreads();
    part[t] += v;
    __syncthreads();
  }
  int run = part[t] - s;
  for (int i = lo; i < hi; ++i) {
    offs[i] = run; cursor[i] = run;
    run += cnt[i];
  }
  if (t == 1023) offs[N] = part[1023];
}

__global__ __launch_bounds__(256) void scatter_ids(
    const int* __restrict__ recv, const int* __restrict__ send,
    int* __restrict__ cursor, int* __restrict__ sorted,
    int* __restrict__ sortedSend, int E)
{
  int e = blockIdx.x * 256 + threadIdx.x;
  if (e >= E) return;
  int pos = atomicAdd(&cursor[recv[e]], 1);
  sorted[pos] = e;
  sortedSend[pos] = send[e];
}

// ---------------- aggregate: 2 waves per node, pipelined masked batches -------
__global__ __launch_bounds__(256) void aggregate(
    const float* __restrict__ nodes, const float* __restrict__ edges,
    const int* __restrict__ offs, const int* __restrict__ sorted,
    const int* __restrict__ sortedSend, unsigned short* __restrict__ S, int N)
{
  __shared__ float4 part[2][64];

  const int tid  = threadIdx.x;
  const int pair = tid >> 7;            // node within block (0..1)
  const int half = (tid >> 6) & 1;      // which wave of the pair
  const int lane = tid & 63;
  const int node = blockIdx.x * 2 + pair;
  if (node >= N) return;

  const int coff = (lane & 31) * 4;
  const bool isNode = lane < 32;
  const int s0 = offs[node], e0 = offs[node + 1];
  const int len = e0 - s0;
  const int mid = s0 + ((len + 1) >> 1);
  int j   = half ? mid : s0;
  const int end = half ? e0 : mid;
  const int* idx = isNode ? sortedSend : sorted;
  const float* base = isNode ? nodes : edges;

  float4 acc = {0.f, 0.f, 0.f, 0.f};
  if (j < end) {
    const int safe = end - 1;
    int eb[8];
    #pragma unroll
    for (int k = 0; k < 8; ++k) eb[k] = idx[min(j + k, safe)];
    while (j < end) {
      // issue all 8 row loads for the current batch
      float4 v[8];
      #pragma unroll
      for (int k = 0; k < 8; ++k)
        v[k] = *reinterpret_cast<const float4*>(base + (size_t)eb[k]*128 + coff);
      // prefetch next batch's indices (overlaps the row loads above)
      int jn = j + 8;
      int eb2[8];
      if (jn < end) {
        #pragma unroll
        for (int k = 0; k < 8; ++k) eb2[k] = idx[min(jn + k, safe)];
      }
      // masked accumulate
      #pragma unroll
      for (int k = 0; k < 8; ++k) {
        if (j + k < end) {
          acc.x += v[k].x; acc.y += v[k].y; acc.z += v[k].z; acc.w += v[k].w;
        }
      }
      #pragma unroll
      for (int k = 0; k < 8; ++k) eb[k] = eb2[k];
      j = jn;
    }
  }

  // combine the two half-waves
  if (half == 1) part[pair][lane] = acc;
  __syncthreads();
  if (half == 0) {
    float4 p = part[pair][lane];
    acc.x += p.x; acc.y += p.y; acc.z += p.z; acc.w += p.w;
    ushort4 o;
    o.x = f2bf(acc.x); o.y = f2bf(acc.y); o.z = f2bf(acc.z); o.w = f2bf(acc.w);
    *reinterpret_cast<ushort4*>(S + (size_t)node * 256 + lane * 4) = o;
  }
}

// ---------------- fused node update: column-split waves, B in registers ------
__device__ inline bf16x8 ldsFragA(const unsigned short* tile, int rowBytes,
                                  int row, int kk, int lg) {
  int byteOff = row * rowBytes + ((((kk << 6) + (lg << 4))) ^ ((row & 7) << 4));
  return *reinterpret_cast<const bf16x8*>(
      reinterpret_cast<const char*>(tile) + byteOff);
}
__device__ inline bf16x8 glbFragB(const unsigned short* WT, int kElems,
                                  int n, int lr, int kk, int lg) {
  size_t el = (size_t)(n*16 + lr) * kElems + kk*32 + lg*8;
  return *reinterpret_cast<const bf16x8*>(WT + el);
}

__global__ __launch_bounds__(256, 3) void fused_node(
    const unsigned short* __restrict__ S, const float* __restrict__ nodes,
    const unsigned short* __restrict__ CmbT, const unsigned short* __restrict__ W0T,
    const unsigned short* __restrict__ W1T, const unsigned short* __restrict__ W2nT,
    const float* __restrict__ b0, const float* __restrict__ b1,
    const float* __restrict__ b2, const float* __restrict__ gam,
    const float* __restrict__ bet, float* __restrict__ out, int N)
{
  __shared__ unsigned short sS[64*256];   // 32KB S tile; bufA=[0,16K), bufB=[16K,32K)
  __shared__ unsigned short sN[64*128];   // 16KB nodes tile
  __shared__ float pS[4][64];
  __shared__ float pQ[4][64];

  unsigned short* bufA = sS;              // agg after G1; h1 after G3
  unsigned short* bufB = sS + 64*128;     // h0 after G2

  const int tid  = threadIdx.x;
  const int lane = tid & 63;
  const int w    = tid >> 6;           // wave: owns cols [w*32, w*32+32)
  const int lr = lane & 15;
  const int lg = lane >> 4;
  const int m0 = blockIdx.x * 64;

  // ---- stage S tile (bf16): 64 rows x 512B, swizzled ----
  #pragma unroll
  for (int it = 0; it < 8; ++it) {
    int c = tid + (it << 8);
    int r = c >> 5, cc = c & 31;
    int gr = m0 + r; if (gr > N-1) gr = N-1;
    bf16x8 v = *reinterpret_cast<const bf16x8*>(S + (size_t)gr*256 + cc*8);
    int dst = r*512 + ((cc << 4) ^ ((r & 7) << 4));
    *reinterpret_cast<bf16x8*>(reinterpret_cast<char*>(sS) + dst) = v;
  }
  // ---- stage nodes tile: f32 -> bf16, swizzled 256B rows ----
  #pragma unroll
  for (int it = 0; it < 4; ++it) {
    int c = tid + (it << 8);
    int r = c >> 4, cc = c & 15;
    int gr = m0 + r; if (gr > N-1) gr = N-1;
    const float4* src = reinterpret_cast<const float4*>(nodes + (size_t)gr*128 + cc*8);
    float4 v0 = src[0], v1 = src[1];
    bf16x8 o;
    o[0]=(short)f2bf(v0.x); o[1]=(short)f2bf(v0.y); o[2]=(short)f2bf(v0.z); o[3]=(short)f2bf(v0.w);
    o[4]=(short)f2bf(v1.x); o[5]=(short)f2bf(v1.y); o[6]=(short)f2bf(v1.z); o[7]=(short)f2bf(v1.w);
    int dst = r*256 + ((cc << 4) ^ ((r & 7) << 4));
    *reinterpret_cast<bf16x8*>(reinterpret_cast<char*>(sN) + dst) = o;
  }

  f32x4 acc[4][2];
  bf16x8 b[2][4];

  // G1 first-half B loads issue before the barrier (global, no LDS dep)
  #pragma unroll
  for (int nn = 0; nn < 2; ++nn)
    #pragma unroll
    for (int kk = 0; kk < 4; ++kk)
      b[nn][kk] = glbFragB(CmbT, 256, w*2 + nn, lr, kk, lg);

  __syncthreads();   // S1: sS + sN staged

  // ======== GEMM1: agg = S(64x256) @ Wm ========
  #pragma unroll
  for (int rb = 0; rb < 4; ++rb)
    #pragma unroll
    for (int nn = 0; nn < 2; ++nn) { acc[rb][nn][0]=0.f; acc[rb][nn][1]=0.f; acc[rb][nn][2]=0.f; acc[rb][nn][3]=0.f; }
  #pragma unroll
  for (int rb = 0; rb < 4; ++rb)
    #pragma unroll
    for (int kk = 0; kk < 4; ++kk) {
      bf16x8 a = ldsFragA(sS, 512, rb*16 + lr, kk, lg);
      #pragma unroll
      for (int nn = 0; nn < 2; ++nn)
        acc[rb][nn] = __builtin_amdgcn_mfma_f32_16x16x32_bf16(a, b[nn][kk], acc[rb][nn], 0, 0, 0);
    }
  #pragma unroll
  for (int nn = 0; nn < 2; ++nn)
    #pragma unroll
    for (int kk = 0; kk < 4; ++kk)
      b[nn][kk] = glbFragB(CmbT, 256, w*2 + nn, lr, kk + 4, lg);
  #pragma unroll
  for (int rb = 0; rb < 4; ++rb)
    #pragma unroll
    for (int kk = 0; kk < 4; ++kk) {
      bf16x8 a = ldsFragA(sS, 512, rb*16 + lr, kk + 4, lg);
      #pragma unroll
      for (int nn = 0; nn < 2; ++nn)
        acc[rb][nn] = __builtin_amdgcn_mfma_f32_16x16x32_bf16(a, b[nn][kk], acc[rb][nn], 0, 0, 0);
    }
  __syncthreads();   // S2: all sS reads done before bufA overwrite

  // epilogue G1 -> bufA (agg)
  #pragma unroll
  for (int rb = 0; rb < 4; ++rb)
    #pragma unroll
    for (int nn = 0; nn < 2; ++nn) {
      int col = w*32 + nn*16 + lr;
      #pragma unroll
      for (int i = 0; i < 4; ++i) {
        int r = rb*16 + lg*4 + i;
        *reinterpret_cast<unsigned short*>(
            reinterpret_cast<char*>(bufA) + r*256 + ((col << 1) ^ ((r & 7) << 4))) = f2bf(acc[rb][nn][i]);
      }
    }
  // G2 first-half B loads (global) before the barrier
  #pragma unroll
  for (int nn = 0; nn < 2; ++nn)
    #pragma unroll
    for (int kk = 0; kk < 4; ++kk)
      b[nn][kk] = glbFragB(W0T, 256, w*2 + nn, lr, kk, lg);
  __syncthreads();   // S3: bufA(agg) ready

  // ======== GEMM2: h0 = relu([nodes, agg] @ w0 + b0) -> bufB ========
  #pragma unroll
  for (int rb = 0; rb < 4; ++rb)
    #pragma unroll
    for (int nn = 0; nn < 2; ++nn) { acc[rb][nn][0]=0.f; acc[rb][nn][1]=0.f; acc[rb][nn][2]=0.f; acc[rb][nn][3]=0.f; }
  #pragma unroll
  for (int rb = 0; rb < 4; ++rb)
    #pragma unroll
    for (int kk = 0; kk < 4; ++kk) {
      bf16x8 a = ldsFragA(sN, 256, rb*16 + lr, kk, lg);
      #pragma unroll
      for (int nn = 0; nn < 2; ++nn)
        acc[rb][nn] = __builtin_amdgcn_mfma_f32_16x16x32_bf16(a, b[nn][kk], acc[rb][nn], 0, 0, 0);
    }
  #pragma unroll
  for (int nn = 0; nn < 2; ++nn)
    #pragma unroll
    for (int kk = 0; kk < 4; ++kk)
      b[nn][kk] = glbFragB(W0T, 256, w*2 + nn, lr, kk + 4, lg);
  #pragma unroll
  for (int rb = 0; rb < 4; ++rb)
    #pragma unroll
    for (int kk = 0; kk < 4; ++kk) {
      bf16x8 a = ldsFragA(bufA, 256, rb*16 + lr, kk, lg);
      #pragma unroll
      for (int nn = 0; nn < 2; ++nn)
        acc[rb][nn] = __builtin_amdgcn_mfma_f32_16x16x32_bf16(a, b[nn][kk], acc[rb][nn], 0, 0, 0);
    }
  // epilogue G2 -> bufB (no barrier needed: bufB untouched by G1/G2 readers)
  #pragma unroll
  for (int nn = 0; nn < 2; ++nn) {
    int col = w*32 + nn*16 + lr;
    float bb = b0[col];
    #pragma unroll
    for (int rb = 0; rb < 4; ++rb)
      #pragma unroll
      for (int i = 0; i < 4; ++i) {
        int r = rb*16 + lg*4 + i;
        float x = fmaxf(acc[rb][nn][i] + bb, 0.f);
        *reinterpret_cast<unsigned short*>(
            reinterpret_cast<char*>(bufB) + r*256 + ((col << 1) ^ ((r & 7) << 4))) = f2bf(x);
      }
  }
  // G3 B loads (K=128 -> single half)
  #pragma unroll
  for (int nn = 0; nn < 2; ++nn)
    #pragma unroll
    for (int kk = 0; kk < 4; ++kk)
      b[nn][kk] = glbFragB(W1T, 128, w*2 + nn, lr, kk, lg);
  __syncthreads();   // S4: bufB(h0) ready; all bufA reads done

  // ======== GEMM3: h1 = relu(h0 @ w1 + b1) -> bufA ========
  #pragma unroll
  for (int rb = 0; rb < 4; ++rb)
    #pragma unroll
    for (int nn = 0; nn < 2; ++nn) { acc[rb][nn][0]=0.f; acc[rb][nn][1]=0.f; acc[rb][nn][2]=0.f; acc[rb][nn][3]=0.f; }
  #pragma unroll
  for (int rb = 0; rb < 4; ++rb)
    #pragma unroll
    for (int kk = 0; kk < 4; ++kk) {
      bf16x8 a = ldsFragA(bufB, 256, rb*16 + lr, kk, lg);
      #pragma unroll
      for (int nn = 0; nn < 2; ++nn)
        acc[rb][nn] = __builtin_amdgcn_mfma_f32_16x16x32_bf16(a, b[nn][kk], acc[rb][nn], 0, 0, 0);
    }
  // epilogue G3 -> bufA (safe: nobody reads bufA now; bufB readers untouched)
  #pragma unroll
  for (int nn = 0; nn < 2; ++nn) {
    int col = w*32 + nn*16 + lr;
    float bb = b1[col];
    #pragma unroll
    for (int rb = 0; rb < 4; ++rb)
      #pragma unroll
      for (int i = 0; i < 4; ++i) {
        int r = rb*16 + lg*4 + i;
        float x = fmaxf(acc[rb][nn][i] + bb, 0.f);
        *reinterpret_cast<unsigned short*>(
            reinterpret_cast<char*>(bufA) + r*256 + ((col << 1) ^ ((r & 7) << 4))) = f2bf(x);
      }
  }
  // G4 first-half B loads
  #pragma unroll
  for (int nn = 0; nn < 2; ++nn)
    #pragma unroll
    for (int kk = 0; kk < 4; ++kk)
      b[nn][kk] = glbFragB(W2nT, 256, w*2 + nn, lr, kk, lg);
  __syncthreads();   // S5: bufA(h1) ready; all bufB reads done

  // ======== GEMM4: o = [h1, nodes] @ [w2; Wnode] + b2, LayerNorm ========
  #pragma unroll
  for (int rb = 0; rb < 4; ++rb)
    #pragma unroll
    for (int nn = 0; nn < 2; ++nn) { acc[rb][nn][0]=0.f; acc[rb][nn][1]=0.f; acc[rb][nn][2]=0.f; acc[rb][nn][3]=0.f; }
  #pragma unroll
  for (int rb = 0; rb < 4; ++rb)
    #pragma unroll
    for (int kk = 0; kk < 4; ++kk) {
      bf16x8 a = ldsFragA(bufA, 256, rb*16 + lr, kk, lg);
      #pragma unroll
      for (int nn = 0; nn < 2; ++nn)
        acc[rb][nn] = __builtin_amdgcn_mfma_f32_16x16x32_bf16(a, b[nn][kk], acc[rb][nn], 0, 0, 0);
    }
  #pragma unroll
  for (int nn = 0; nn < 2; ++nn)
    #pragma unroll
    for (int kk = 0; kk < 4; ++kk)
      b[nn][kk] = glbFragB(W2nT, 256, w*2 + nn, lr, kk + 4, lg);
  #pragma unroll
  for (int rb = 0; rb < 4; ++rb)
    #pragma unroll
    for (int kk = 0; kk < 4; ++kk) {
      bf16x8 a = ldsFragA(sN, 256, rb*16 + lr, kk, lg);
      #pragma unroll
      for (int nn = 0; nn < 2; ++nn)
        acc[rb][nn] = __builtin_amdgcn_mfma_f32_16x16x32_bf16(a, b[nn][kk], acc[rb][nn], 0, 0, 0);
    }
  // bias
  #pragma unroll
  for (int nn = 0; nn < 2; ++nn) {
    float bb = b2[w*32 + nn*16 + lr];
    #pragma unroll
    for (int rb = 0; rb < 4; ++rb)
      #pragma unroll
      for (int i = 0; i < 4; ++i) acc[rb][nn][i] += bb;
  }

  // ---- LayerNorm: cross-wave row reduction via LDS partials ----
  float rs[4][4], rq[4][4];
  #pragma unroll
  for (int rb = 0; rb < 4; ++rb)
    #pragma unroll
    for (int i = 0; i < 4; ++i) {
      float a0 = acc[rb][0][i], a1 = acc[rb][1][i];
      rs[rb][i] = a0 + a1;
      rq[rb][i] = a0*a0 + a1*a1;
    }
  #pragma unroll
  for (int msk = 1; msk < 16; msk <<= 1)
    #pragma unroll
    for (int rb = 0; rb < 4; ++rb)
      #pragma unroll
      for (int i = 0; i < 4; ++i) {
        rs[rb][i] += __shfl_xor(rs[rb][i], msk);
        rq[rb][i] += __shfl_xor(rq[rb][i], msk);
      }
  if (lr == 0) {
    #pragma unroll
    for (int rb = 0; rb < 4; ++rb)
      #pragma unroll
      for (int i = 0; i < 4; ++i) {
        int r = rb*16 + lg*4 + i;
        pS[w][r] = rs[rb][i];
        pQ[w][r] = rq[rb][i];
      }
  }
  __syncthreads();

  float gmul[2], gadd[2];
  #pragma unroll
  for (int nn = 0; nn < 2; ++nn) {
    int col = w*32 + nn*16 + lr;
    gmul[nn] = gam[col]; gadd[nn] = bet[col];
  }
  #pragma unroll
  for (int rb = 0; rb < 4; ++rb)
    #pragma unroll
    for (int i = 0; i < 4; ++i) {
      int r = rb*16 + lg*4 + i;
      float sum = pS[0][r] + pS[1][r] + pS[2][r] + pS[3][r];
      float sq  = pQ[0][r] + pQ[1][r] + pQ[2][r] + pQ[3][r];
      float mean = sum * (1.f/128.f);
      float var  = fmaxf(sq * (1.f/128.f) - mean*mean, 0.f);
      float rstd = rsqrtf(var + 1e-6f);
      int grow = m0 + r;
      if (grow < N) {
        #pragma unroll
        for (int nn = 0; nn < 2; ++nn) {
          int col = w*32 + nn*16 + lr;
          out[(size_t)grow*128 + col] = (acc[rb][nn][i] - mean) * rstd * gmul[nn] + gadd[nn];
        }
      }
    }
}

extern "C" void kernel_launch(void* const* d_in, const int* in_sizes, int n_in,
                              void* d_out, int out_size, void* d_ws, size_t ws_size,
                              hipStream_t stream) {
  const float* nodes     = (const float*)d_in[0];
  const float* edges     = (const float*)d_in[1];
  const int*   senders   = (const int*)d_in[2];
  const int*   receivers = (const int*)d_in[3];
  const float* Wm  = (const float*)d_in[4];
  const float* Wn  = (const float*)d_in[5];
  const float* w0  = (const float*)d_in[6];
  const float* b0  = (const float*)d_in[7];
  const float* w1  = (const float*)d_in[8];
  const float* b1  = (const float*)d_in[9];
  const float* w2  = (const float*)d_in[10];
  const float* b2  = (const float*)d_in[11];
  const float* gam = (const float*)d_in[12];
  const float* bet = (const float*)d_in[13];
  const int N = in_sizes[0] / 128;
  const int E = in_sizes[1] / 128;

  char* ws = (char*)d_ws;
  unsigned short* S = (unsigned short*)ws;                 // [N][256] bf16
  size_t sBytes = (size_t)N * 256 * 2;
  unsigned short* CmbT = (unsigned short*)(ws + sBytes);   // [128][256]
  unsigned short* W0T  = CmbT + 128*256;                   // [128][256]
  unsigned short* W1T  = W0T + 128*256;                    // [128][128]
  unsigned short* W2nT = W1T + 128*128;                    // [128][256]
  int* cnt        = (int*)(W2nT + 128*256);                // [N]
  int* offs       = cnt + N;                               // [N+1]
  int* cursor     = offs + N + 1;                          // [N]
  int* sorted     = cursor + N;                            // [E]
  int* sortedSend = sorted + E;                            // [E]

  int zBlocks = (N + 2047) / 2048;
  prep_zero<<<128 + zBlocks, 256, 0, stream>>>(Wm, w0, w1, w2, Wn,
                                               CmbT, W0T, W1T, W2nT, cnt, N);

  int eBlocks = (E + 255) / 256;
  hist_recv<<<eBlocks, 256, 0, stream>>>(receivers, cnt, E);
  scan_counts<<<1, 1024, 0, stream>>>(cnt, offs, cursor, N);
  scatter_ids<<<eBlocks, 256, 0, stream>>>(receivers, senders, cursor, sorted, sortedSend, E);

  int aggBlocks = (N + 1) / 2;
  aggregate<<<aggBlocks, 256, 0, stream>>>(nodes, edges, offs, sorted, sortedSend, S, N);

  int nodeBlocks = (N + 63) / 64;
  fused_node<<<nodeBlocks, 256, 0, stream>>>(S, nodes, CmbT, W0T, W1T, W2nT,
                                             b0, b1, b2, gam, bet, (float*)d_out, N);
}